// Round 11
// baseline (704.065 us; speedup 1.0000x reference)
//
#include <hip/hip_runtime.h>
#include <hip/hip_bf16.h>
#include <math.h>

#define NFM 512   // NFMODES
#define NE  256
#define NUN 32    // NUNPAIRED
#define NM  480   // NMODES
#define NB  32    // BATCH
#define NF  288   // NE + NUN  (Ffull dim)
#define WP  16    // panel width
#define PAIRS 8   // WP/2
#define PP  17    // panel LDS pitch (odd -> conflict-free)
#define THETA 0.03125f

typedef unsigned long long ull;

// ---------------- Ja = (J - J^T)/2 ----------------
__global__ __launch_bounds__(256)
void build_ja_k(const float* __restrict__ J, float* __restrict__ Ja) {
  int t = blockIdx.x * blockDim.x + threadIdx.x;
  int stride = gridDim.x * blockDim.x;
  for (int e = t; e < NM * NM; e += stride) {
    int i = e / NM, j = e - i * NM;
    Ja[e] = 0.5f * (J[i * NM + j] - J[j * NM + i]);
  }
}

// ---------------- Tmp[b] (256x480) = Up_b @ Ja ----------
__global__ __launch_bounds__(256)
void gemm1_k(const float* __restrict__ U, const int* __restrict__ idx,
             const float* __restrict__ Ja, float* __restrict__ Tmp) {
  const int b  = blockIdx.z;
  const int m0 = blockIdx.y << 6;
  const int n0 = blockIdx.x << 6;
  const int tid = threadIdx.x;
  __shared__ float As[16][64];
  __shared__ float Bs[16][64];
  const int ar = tid >> 2, ac = (tid & 3) << 2;
  const int br = tid >> 4, bc = (tid & 15) << 2;
  const int tx = tid & 15, ty = tid >> 4;
  const float* Arow = U + (size_t)idx[b * NE + m0 + ar] * NFM + NUN;
  float acc[4][4] = {};
  for (int l0 = 0; l0 < NM; l0 += 16) {
    float4 av = *(const float4*)(Arow + l0 + ac);
    As[ac + 0][ar] = av.x; As[ac + 1][ar] = av.y;
    As[ac + 2][ar] = av.z; As[ac + 3][ar] = av.w;
    float4 bv = make_float4(0.f, 0.f, 0.f, 0.f);
    if (n0 + bc < NM) bv = *(const float4*)(Ja + (size_t)(l0 + br) * NM + n0 + bc);
    *(float4*)(&Bs[br][bc]) = bv;
    __syncthreads();
#pragma unroll
    for (int kk = 0; kk < 16; ++kk) {
      float4 a4 = *(const float4*)(&As[kk][ty << 2]);
      float4 b4 = *(const float4*)(&Bs[kk][tx << 2]);
      float a[4] = {a4.x, a4.y, a4.z, a4.w};
      float bb[4] = {b4.x, b4.y, b4.z, b4.w};
#pragma unroll
      for (int q = 0; q < 4; ++q)
#pragma unroll
        for (int p = 0; p < 4; ++p) acc[q][p] = fmaf(a[q], bb[p], acc[q][p]);
    }
    __syncthreads();
  }
  float* Tb = Tmp + (size_t)b * NE * NM;
#pragma unroll
  for (int q = 0; q < 4; ++q) {
    int r = m0 + (ty << 2) + q;
#pragma unroll
    for (int p = 0; p < 4; ++p) {
      int m = n0 + (tx << 2) + p;
      if (m < NM) Tb[(size_t)r * NM + m] = acc[q][p];
    }
  }
}

// ---------------- F[b] = Tmp[b] @ Up_b^T  -> Ffull[0:256][0:256] ------------
__global__ __launch_bounds__(256)
void gemm2_k(const float* __restrict__ U, const int* __restrict__ idx,
             const float* __restrict__ Tmp, float* __restrict__ Ff) {
  const int b  = blockIdx.z;
  const int m0 = blockIdx.y << 6;
  const int n0 = blockIdx.x << 6;
  const int tid = threadIdx.x;
  __shared__ float As[16][64];
  __shared__ float Bs[16][64];
  const int ar = tid >> 2, ac = (tid & 3) << 2;
  const int jr = tid >> 2, kc = (tid & 3) << 2;
  const int tx = tid & 15, ty = tid >> 4;
  const float* Arow = Tmp + ((size_t)b * NE + m0 + ar) * NM;
  const float* Brow = U + (size_t)idx[b * NE + n0 + jr] * NFM + NUN;
  float acc[4][4] = {};
  for (int l0 = 0; l0 < NM; l0 += 16) {
    float4 av = *(const float4*)(Arow + l0 + ac);
    As[ac + 0][ar] = av.x; As[ac + 1][ar] = av.y;
    As[ac + 2][ar] = av.z; As[ac + 3][ar] = av.w;
    float4 bv = *(const float4*)(Brow + l0 + kc);
    Bs[kc + 0][jr] = bv.x; Bs[kc + 1][jr] = bv.y;
    Bs[kc + 2][jr] = bv.z; Bs[kc + 3][jr] = bv.w;
    __syncthreads();
#pragma unroll
    for (int kk = 0; kk < 16; ++kk) {
      float4 a4 = *(const float4*)(&As[kk][ty << 2]);
      float4 b4 = *(const float4*)(&Bs[kk][tx << 2]);
      float a[4] = {a4.x, a4.y, a4.z, a4.w};
      float bb[4] = {b4.x, b4.y, b4.z, b4.w};
#pragma unroll
      for (int q = 0; q < 4; ++q)
#pragma unroll
        for (int p = 0; p < 4; ++p) acc[q][p] = fmaf(a[q], bb[p], acc[q][p]);
    }
    __syncthreads();
  }
  float* Fb = Ff + (size_t)b * NF * NF;
#pragma unroll
  for (int q = 0; q < 4; ++q) {
    int i = m0 + (ty << 2) + q;
#pragma unroll
    for (int p = 0; p < 4; ++p) {
      int j = n0 + (tx << 2) + p;
      Fb[(size_t)i * NF + j] = acc[q][p];
    }
  }
}

// ---------------- edges ---------------
__global__ __launch_bounds__(256)
void fill_edges_k(const float* __restrict__ U, const int* __restrict__ idx,
                  float* __restrict__ Ff) {
  const int b = blockIdx.x;
  const int tid = threadIdx.x;
  float* Fb = Ff + (size_t)b * NF * NF;
  const int gr = idx[b * NE + tid];
#pragma unroll 4
  for (int u = 0; u < NUN; ++u) {
    float v = U[(size_t)gr * NFM + u];
    Fb[(size_t)tid * NF + NE + u] = v;
    Fb[(size_t)(NE + u) * NF + tid] = -v;
  }
  if (tid < NUN) {
    for (int v = 0; v < NUN; ++v) Fb[(size_t)(NE + tid) * NF + NE + v] = 0.f;
  }
}

// ---------------- Pfaffian: blocked Parlett-Reid, SINGLE-WAVE factor --------
// Invariant: A_cur[i][j] = snapshot[i][j] + sum_m iv_m*(nu_m[i]c_m[j]-c_m[i]nu_m[j])
// snapshot = P (panel cols, LDS) + global A (trailing cols). nu = -A_cur[:,k].
// Wave 0 factors the whole panel barrier-free (lane owns rows lane+64w);
// pivot/pivdef extracted via __shfl from holder lanes; deferred corrections
// read broadcast coefficients. Swap steps (rare, threshold) use R6-verified
// algebra in 5-slot single-wave form. Waves 1-7 join for load + trailing.
__global__ __launch_bounds__(512)
void pfpanel_k(float* __restrict__ Ff, float* __restrict__ out) {
  const int b = blockIdx.x;
  float* __restrict__ A = Ff + (size_t)b * NF * NF;
  const int tid = threadIdx.x;
  const int lane = tid & 63;
  __shared__ __align__(16) float P[NF * PP];
  __shared__ __align__(16) float s_nu[PAIRS][NF];
  __shared__ __align__(16) float s_c[PAIRS][NF];
  __shared__ float s_invp[PAIRS];
  __shared__ float s_oldrow[WP];

  float sign = 1.f, logabs = 0.f;   // wave-0 lane-0 only

#pragma unroll 1
  for (int k0 = 0; k0 < NF; k0 += WP) {
    const int pend = k0 + WP;

    // ---- panel load (all threads): P[r][0..15] = A[r][k0..k0+15] ----
    for (int e = tid; e < NF * 4; e += 512) {
      int r = e >> 2, c4 = (e & 3) << 2;
      float4 v = *(const float4*)(A + (size_t)r * NF + k0 + c4);
      float* d = P + r * PP + c4;
      d[0] = v.x; d[1] = v.y; d[2] = v.z; d[3] = v.w;
    }
    __syncthreads();

    if (tid < 64) {
      // ================= single-wave panel factorization =================
#pragma unroll 1
      for (int mp = 0; mp < PAIRS; ++mp) {
        const int k = k0 + 2 * mp, lc = 2 * mp, lc1 = lc + 1;

        // ---- pair columns + deferred corrections ----
        float vk[5], vk1[5];
#pragma unroll
        for (int w = 0; w < 5; ++w) {
          int r = lane + (w << 6);
          bool live = (r > k) && (r < NF);
          vk[w]  = live ? P[r * PP + lc]  : 0.f;
          vk1[w] = live ? P[r * PP + lc1] : 0.f;
        }
#pragma unroll 1
        for (int m = 0; m < mp; ++m) {
          float im  = s_invp[m];
          float ak  = im * s_nu[m][k],     bk  = im * s_c[m][k];
          float ak1 = im * s_nu[m][k + 1], bk1 = im * s_c[m][k + 1];
#pragma unroll
          for (int w = 0; w < 5; ++w) {
            int r = lane + (w << 6);
            if (r > k && r < NF) {
              float nu_i = s_nu[m][r], c_i = s_c[m][r];
              vk[w]  = fmaf(nu_i, bk,  fmaf(-c_i, ak,  vk[w]));
              vk1[w] = fmaf(nu_i, bk1, fmaf(-c_i, ak1, vk1[w]));
            }
          }
        }

        // ---- pivdef (row k+1's column-k value) via shfl ----
        const int sK1 = (k + 1) >> 6, lK1 = (k + 1) & 63;
        float vsel = sK1 == 0 ? vk[0] : sK1 == 1 ? vk[1] : sK1 == 2 ? vk[2]
                   : sK1 == 3 ? vk[3] : vk[4];
        const float pivdef = __shfl(vsel, lK1, 64);

        // ---- butterfly argmax ----
        ull pk = 0;
#pragma unroll
        for (int w = 0; w < 5; ++w) {
          int r = lane + (w << 6);
          if (r > k && r < NF) {
            ull cand = ((ull)__float_as_uint(fabsf(vk[w])) << 32) | (ull)(NF - r);
            if (cand > pk) pk = cand;
          }
        }
#pragma unroll
        for (int s = 32; s > 0; s >>= 1) {
          ull o = __shfl_xor(pk, s, 64);
          if (o > pk) pk = o;
        }
        const float vmax = __uint_as_float((unsigned)(pk >> 32));
        const bool doswap = fabsf(pivdef) < THETA * vmax;
        int kp; float pivot;
        if (!doswap) { kp = k + 1; pivot = -pivdef; }
        else {
          kp = NF - (int)(pk & 0xffffffffULL);
          const int sKp = kp >> 6, lKp = kp & 63;
          float vs2 = sKp == 0 ? vk[0] : sKp == 1 ? vk[1] : sKp == 2 ? vk[2]
                    : sKp == 3 ? vk[3] : vk[4];
          pivot = -__shfl(vs2, lKp, 64);
        }
        const float invp = 1.f / pivot;
        (void)invp;
        if (lane == 0) {
          if (doswap) sign = -sign;
          sign *= (pivot > 0.f ? 1.f : (pivot < 0.f ? -1.f : 0.f));
          logabs += logf(fabsf(pivot));
          s_invp[mp] = invp;
        }

        if (!doswap) {
          // ---- common path: stage pair from registers ----
#pragma unroll
          for (int w = 0; w < 5; ++w) {
            int r = lane + (w << 6);
            if (r > k + 1 && r < NF) { s_nu[mp][r] = -vk[w]; s_c[mp][r] = vk1[w]; }
          }
        } else if (kp < pend) {
          // ================= case B: in-panel swap =================
          const int lckp = kp - k0;
#pragma unroll
          for (int w = 0; w < 5; ++w) {
            int r = lane + (w << 6);
            if (r > k + 1 && r < NF && r != kp) {
              float a1 = P[r * PP + lc1], a2 = P[r * PP + lckp];
              P[r * PP + lc1] = a2; P[r * PP + lckp] = a1;
            }
          }
          if (lane < WP && lane != lc1 && lane != lckp) {
            float a1 = P[(k + 1) * PP + lane], a2 = P[kp * PP + lane];
            P[(k + 1) * PP + lane] = a2; P[kp * PP + lane] = a1;
          }
          if (lane == 0) {
            float a1 = P[kp * PP + lc1];         // old A[kp][k+1]
            float a2 = P[(k + 1) * PP + lckp];   // old A[k+1][kp]
            P[(k + 1) * PP + lc1] = 0.f;  P[(k + 1) * PP + lckp] = a1;
            P[kp * PP + lc1] = a2;        P[kp * PP + lckp] = 0.f;
          }
          if (lane < mp) {
            int m = lane;
            float a1 = s_nu[m][k + 1]; s_nu[m][k + 1] = s_nu[m][kp]; s_nu[m][kp] = a1;
            float a2 = s_c[m][k + 1];  s_c[m][k + 1]  = s_c[m][kp];  s_c[m][kp]  = a2;
          }
          // restage (post-swap snapshot + corrections with post-swap entries)
#pragma unroll
          for (int w = 0; w < 5; ++w) {
            int r = lane + (w << 6);
            if (r > k + 1 && r < NF) {
              float vpost = (r == kp) ? pivdef : vk[w];
              float cc = P[r * PP + lc1];
#pragma unroll 1
              for (int m = 0; m < mp; ++m) {
                float im = s_invp[m];
                float ak1 = im * s_nu[m][k + 1], bk1 = im * s_c[m][k + 1];
                cc = fmaf(s_nu[m][r], bk1, fmaf(-s_c[m][r], ak1, cc));
              }
              s_nu[mp][r] = -vpost; s_c[mp][r] = cc;
            }
          }
        } else {
          // ================= case C: trailing swap =================
          if (lane < WP) s_oldrow[lane] = P[kp * PP + lane];
          if (lane < WP) P[kp * PP + lane] = P[(k + 1) * PP + lane];
          if (lane < mp) {
            int m = lane;
            float a1 = s_nu[m][k + 1]; s_nu[m][k + 1] = s_nu[m][kp]; s_nu[m][kp] = a1;
            float a2 = s_c[m][k + 1];  s_c[m][k + 1]  = s_c[m][kp];  s_c[m][kp]  = a2;
          }
          float gvr[5];
#pragma unroll
          for (int w = 0; w < 5; ++w) {
            int r = lane + (w << 6);
            gvr[w] = 0.f;
            if (r > k + 1 && r < NF) {
              if (r == kp) {
                A[(size_t)kp * NF + kp] = 0.f;
              } else if (r >= pend) {
                float pvv = P[r * PP + lc1];
                gvr[w] = A[(size_t)r * NF + kp];
                A[(size_t)r * NF + kp] = pvv;
                A[(size_t)kp * NF + r] = -pvv;
              }
            }
          }
          // restage
#pragma unroll
          for (int w = 0; w < 5; ++w) {
            int r = lane + (w << 6);
            if (r > k + 1 && r < NF) {
              float vpost = (r == kp) ? pivdef : vk[w];
              float cc;
              if (r < pend)     cc = -s_oldrow[r - k0];
              else if (r == kp) cc = -s_oldrow[lc1];
              else              cc = gvr[w];
#pragma unroll 1
              for (int m = 0; m < mp; ++m) {
                float im = s_invp[m];
                float ak1 = im * s_nu[m][k + 1], bk1 = im * s_c[m][k + 1];
                cc = fmaf(s_nu[m][r], bk1, fmaf(-s_c[m][r], ak1, cc));
              }
              s_nu[mp][r] = -vpost; s_c[mp][r] = cc;
            }
          }
        }
      }
    }
    __syncthreads();   // factor results visible to all waves

    // ---- panel-end: j-outer rank-8 x2 streaming update of trailing block --
    if (pend < NF) {
      const int ty = tid >> 6, tx = tid & 63;
      const int nch = (NF - pend) >> 2;
      float ivr[PAIRS];
#pragma unroll
      for (int m = 0; m < PAIRS; ++m) ivr[m] = s_invp[m];
#pragma unroll 1
      for (int g = 0; g < 2; ++g) {
        for (int jb = 0; jb < nch; jb += 64) {
          const int j4 = jb + tx;
          if (j4 < nch) {
            const int j = pend + (j4 << 2);
            float4 cj[4], tj[4];
#pragma unroll
            for (int m = 0; m < 4; ++m) {
              const int mm = g * 4 + m;
              float4 n4 = *(const float4*)(&s_nu[mm][j]);
              cj[m] = *(const float4*)(&s_c[mm][j]);
              const float im = ivr[mm];
              tj[m] = make_float4(n4.x * im, n4.y * im, n4.z * im, n4.w * im);
            }
#pragma unroll 2
            for (int i = pend + ty; i < NF; i += 8) {
              float* ap = A + (size_t)i * NF + j;
              float4 a = *(float4*)ap;
#pragma unroll
              for (int m = 0; m < 4; ++m) {
                const int mm = g * 4 + m;
                const float ti = s_nu[mm][i] * ivr[mm];
                const float ci = s_c[mm][i];
                a.x = fmaf(ti, cj[m].x, fmaf(-ci, tj[m].x, a.x));
                a.y = fmaf(ti, cj[m].y, fmaf(-ci, tj[m].y, a.y));
                a.z = fmaf(ti, cj[m].z, fmaf(-ci, tj[m].z, a.z));
                a.w = fmaf(ti, cj[m].w, fmaf(-ci, tj[m].w, a.w));
              }
              *(float4*)ap = a;
            }
          }
        }
      }
    }
    __syncthreads();   // trailing writes visible to next panel load
  }

  if (tid == 0) { out[b] = sign; out[NB + b] = logabs; }
}

extern "C" void kernel_launch(void* const* d_in, const int* in_sizes, int n_in,
                              void* d_out, int out_size, void* d_ws, size_t ws_size,
                              hipStream_t stream) {
  const float* U  = (const float*)d_in[0];
  const float* J  = (const float*)d_in[1];
  const int* idx  = (const int*)d_in[2];
  float* out = (float*)d_out;
  float* ws = (float*)d_ws;

  float* Ja  = ws;                          // 480*480
  float* Tmp = Ja + (size_t)NM * NM;        // 32*256*480
  float* Ff  = Tmp + (size_t)NB * NE * NM;  // 32*288*288

  build_ja_k<<<dim3(256), dim3(256), 0, stream>>>(J, Ja);
  gemm1_k<<<dim3(8, 4, NB), dim3(256), 0, stream>>>(U, idx, Ja, Tmp);
  gemm2_k<<<dim3(4, 4, NB), dim3(256), 0, stream>>>(U, idx, Tmp, Ff);
  fill_edges_k<<<dim3(NB), dim3(256), 0, stream>>>(U, idx, Ff);
  pfpanel_k<<<dim3(NB), dim3(512), 0, stream>>>(Ff, out);
}

// Round 12
// 574.686 us; speedup vs baseline: 1.2251x; 1.2251x over previous
//
#include <hip/hip_runtime.h>
#include <hip/hip_bf16.h>
#include <math.h>

#define NFM 512   // NFMODES
#define NE  256
#define NUN 32    // NUNPAIRED
#define NM  480   // NMODES
#define NB  32    // BATCH
#define NF  288   // NE + NUN  (Ffull dim)
#define WP  16    // panel width
#define PAIRS 8   // WP/2
#define PP  18    // panel LDS pitch (even -> float2-aligned)
#define THETA 0.03125f

typedef unsigned long long ull;

// ---------------- Ja = (J - J^T)/2 ----------------
__global__ __launch_bounds__(256)
void build_ja_k(const float* __restrict__ J, float* __restrict__ Ja) {
  int t = blockIdx.x * blockDim.x + threadIdx.x;
  int stride = gridDim.x * blockDim.x;
  for (int e = t; e < NM * NM; e += stride) {
    int i = e / NM, j = e - i * NM;
    Ja[e] = 0.5f * (J[i * NM + j] - J[j * NM + i]);
  }
}

// ---------------- Tmp[b] (256x480) = Up_b @ Ja ----------
__global__ __launch_bounds__(256)
void gemm1_k(const float* __restrict__ U, const int* __restrict__ idx,
             const float* __restrict__ Ja, float* __restrict__ Tmp) {
  const int b  = blockIdx.z;
  const int m0 = blockIdx.y << 6;
  const int n0 = blockIdx.x << 6;
  const int tid = threadIdx.x;
  __shared__ float As[16][64];
  __shared__ float Bs[16][64];
  const int ar = tid >> 2, ac = (tid & 3) << 2;
  const int br = tid >> 4, bc = (tid & 15) << 2;
  const int tx = tid & 15, ty = tid >> 4;
  const float* Arow = U + (size_t)idx[b * NE + m0 + ar] * NFM + NUN;
  float acc[4][4] = {};
  for (int l0 = 0; l0 < NM; l0 += 16) {
    float4 av = *(const float4*)(Arow + l0 + ac);
    As[ac + 0][ar] = av.x; As[ac + 1][ar] = av.y;
    As[ac + 2][ar] = av.z; As[ac + 3][ar] = av.w;
    float4 bv = make_float4(0.f, 0.f, 0.f, 0.f);
    if (n0 + bc < NM) bv = *(const float4*)(Ja + (size_t)(l0 + br) * NM + n0 + bc);
    *(float4*)(&Bs[br][bc]) = bv;
    __syncthreads();
#pragma unroll
    for (int kk = 0; kk < 16; ++kk) {
      float4 a4 = *(const float4*)(&As[kk][ty << 2]);
      float4 b4 = *(const float4*)(&Bs[kk][tx << 2]);
      float a[4] = {a4.x, a4.y, a4.z, a4.w};
      float bb[4] = {b4.x, b4.y, b4.z, b4.w};
#pragma unroll
      for (int q = 0; q < 4; ++q)
#pragma unroll
        for (int p = 0; p < 4; ++p) acc[q][p] = fmaf(a[q], bb[p], acc[q][p]);
    }
    __syncthreads();
  }
  float* Tb = Tmp + (size_t)b * NE * NM;
#pragma unroll
  for (int q = 0; q < 4; ++q) {
    int r = m0 + (ty << 2) + q;
#pragma unroll
    for (int p = 0; p < 4; ++p) {
      int m = n0 + (tx << 2) + p;
      if (m < NM) Tb[(size_t)r * NM + m] = acc[q][p];
    }
  }
}

// ---------------- F[b] = Tmp[b] @ Up_b^T  -> Ffull[0:256][0:256] ------------
__global__ __launch_bounds__(256)
void gemm2_k(const float* __restrict__ U, const int* __restrict__ idx,
             const float* __restrict__ Tmp, float* __restrict__ Ff) {
  const int b  = blockIdx.z;
  const int m0 = blockIdx.y << 6;
  const int n0 = blockIdx.x << 6;
  const int tid = threadIdx.x;
  __shared__ float As[16][64];
  __shared__ float Bs[16][64];
  const int ar = tid >> 2, ac = (tid & 3) << 2;
  const int jr = tid >> 2, kc = (tid & 3) << 2;
  const int tx = tid & 15, ty = tid >> 4;
  const float* Arow = Tmp + ((size_t)b * NE + m0 + ar) * NM;
  const float* Brow = U + (size_t)idx[b * NE + n0 + jr] * NFM + NUN;
  float acc[4][4] = {};
  for (int l0 = 0; l0 < NM; l0 += 16) {
    float4 av = *(const float4*)(Arow + l0 + ac);
    As[ac + 0][ar] = av.x; As[ac + 1][ar] = av.y;
    As[ac + 2][ar] = av.z; As[ac + 3][ar] = av.w;
    float4 bv = *(const float4*)(Brow + l0 + kc);
    Bs[kc + 0][jr] = bv.x; Bs[kc + 1][jr] = bv.y;
    Bs[kc + 2][jr] = bv.z; Bs[kc + 3][jr] = bv.w;
    __syncthreads();
#pragma unroll
    for (int kk = 0; kk < 16; ++kk) {
      float4 a4 = *(const float4*)(&As[kk][ty << 2]);
      float4 b4 = *(const float4*)(&Bs[kk][tx << 2]);
      float a[4] = {a4.x, a4.y, a4.z, a4.w};
      float bb[4] = {b4.x, b4.y, b4.z, b4.w};
#pragma unroll
      for (int q = 0; q < 4; ++q)
#pragma unroll
        for (int p = 0; p < 4; ++p) acc[q][p] = fmaf(a[q], bb[p], acc[q][p]);
    }
    __syncthreads();
  }
  float* Fb = Ff + (size_t)b * NF * NF;
#pragma unroll
  for (int q = 0; q < 4; ++q) {
    int i = m0 + (ty << 2) + q;
#pragma unroll
    for (int p = 0; p < 4; ++p) {
      int j = n0 + (tx << 2) + p;
      Fb[(size_t)i * NF + j] = acc[q][p];
    }
  }
}

// ---------------- edges ---------------
__global__ __launch_bounds__(256)
void fill_edges_k(const float* __restrict__ U, const int* __restrict__ idx,
                  float* __restrict__ Ff) {
  const int b = blockIdx.x;
  const int tid = threadIdx.x;
  float* Fb = Ff + (size_t)b * NF * NF;
  const int gr = idx[b * NE + tid];
#pragma unroll 4
  for (int u = 0; u < NUN; ++u) {
    float v = U[(size_t)gr * NFM + u];
    Fb[(size_t)tid * NF + NE + u] = v;
    Fb[(size_t)(NE + u) * NF + tid] = -v;
  }
  if (tid < NUN) {
    for (int v = 0; v < NUN; ++v) Fb[(size_t)(NE + tid) * NF + NE + v] = 0.f;
  }
}

// ---------------- Pfaffian: blocked Parlett-Reid, threshold pivoting --------
// EXACTLY the round-5 factor structure (measured 362 us): float2 s_tc (tau
// pre-scaled by 1/pivot, c raw), deferred corrections (3 float2 loads per
// past pair), 2-barrier common step, 3-barrier swap steps (rare under theta).
// ONLY the trailing pass differs: j-outer with register-cached column
// fragments (2 x rank-4 passes), ~30x fewer LDS wave-ops than the i-outer
// per-row coefficient re-reads.
__global__ __launch_bounds__(512)
void pfpanel_k(float* __restrict__ Ff, float* __restrict__ out) {
  const int b = blockIdx.x;
  float* __restrict__ A = Ff + (size_t)b * NF * NF;
  const int tid = threadIdx.x;
  __shared__ __align__(16) float P[NF * PP];
  __shared__ __align__(16) float2 s_tc[PAIRS][NF];   // (tau, c) interleaved
  __shared__ __align__(16) float s_colbuf[NF];
  __shared__ float s_oldrow[WP];
  __shared__ ull s_red[8];

  float sign = 1.f, logabs = 0.f;   // thread 0 only

#pragma unroll 1
  for (int k0 = 0; k0 < NF; k0 += WP) {
    const int pend = k0 + WP;

    // ---- panel load: P[r][0..15] = A[r][k0..k0+15] ----
    for (int e = tid; e < NF * 4; e += 512) {
      int r = e >> 2, c4 = (e & 3) << 2;
      float4 v = *(const float4*)(A + (size_t)r * NF + k0 + c4);
      float2* d = (float2*)&P[r * PP + c4];
      d[0] = make_float2(v.x, v.y);
      d[1] = make_float2(v.z, v.w);
    }
    __syncthreads();

#pragma unroll 1
    for (int mp = 0; mp < PAIRS; ++mp) {
      const int k = k0 + 2 * mp, lc = 2 * mp, lc1 = lc + 1;

      // ---- phase 1: both pair columns + corrections (registers) + max -----
      float vk = 0.f, vk1 = 0.f;
      ull pk = 0;
      if (tid > k && tid < NF) {
        float2 pv = *(const float2*)&P[tid * PP + lc];
        vk = pv.x; vk1 = pv.y;
        for (int m = 0; m < mp; ++m) {
          float2 ti  = s_tc[m][tid];
          float2 tk  = s_tc[m][k];
          float2 tk1 = s_tc[m][k + 1];
          vk  = fmaf(ti.x, tk.y,  fmaf(-ti.y, tk.x,  vk));
          vk1 = fmaf(ti.x, tk1.y, fmaf(-ti.y, tk1.x, vk1));
        }
        s_colbuf[tid] = vk;
        pk = ((ull)__float_as_uint(fabsf(vk)) << 32) | (ull)(NF - tid);
      }
#pragma unroll
      for (int m = 32; m > 0; m >>= 1) {
        ull o = __shfl_xor(pk, m, 64);
        if (o > pk) pk = o;
      }
      if ((tid & 63) == 0) s_red[tid >> 6] = pk;
      __syncthreads();                                    // B1
      ull best = s_red[0];
#pragma unroll
      for (int w = 1; w < 8; ++w) if (s_red[w] > best) best = s_red[w];
      const float vmax = __uint_as_float((unsigned)(best >> 32));
      const float pivdef = -s_colbuf[k + 1];
      const bool doswap = fabsf(pivdef) < THETA * vmax;
      const int kp = doswap ? (NF - (int)(best & 0xffffffffULL)) : (k + 1);
      const float pivot = doswap ? -s_colbuf[kp] : pivdef;
      const float invp = 1.f / pivot;
      if (tid == 0) {
        if (kp != k + 1) sign = -sign;
        sign *= (pivot > 0.f ? 1.f : (pivot < 0.f ? -1.f : 0.f));
        logabs += logf(fabsf(pivot));
      }

      if (!doswap) {
        // ================= common path: no swap, stage from registers ======
        if (tid > k + 1 && tid < NF)
          s_tc[mp][tid] = make_float2(-vk * invp, vk1);
        __syncthreads();                                  // B2
      } else {
        const bool inpanel = (kp < pend);
        float gvr = 0.f;
        if (inpanel) {
          // ---- case B: in-panel swap ----
          const int lckp = kp - k0;
          if (tid > k + 1 && tid < NF && tid != kp) {
            float a = P[tid * PP + lc1], b2 = P[tid * PP + lckp];
            P[tid * PP + lc1] = b2; P[tid * PP + lckp] = a;
          } else if (tid >= NF && tid < NF + WP) {
            int c = tid - NF;
            if (c != lc1 && c != lckp) {
              float a = P[(k + 1) * PP + c], b2 = P[kp * PP + c];
              P[(k + 1) * PP + c] = b2; P[kp * PP + c] = a;
            }
          } else if (tid == NF + WP) {
            float a = P[kp * PP + lc1];         // old A[kp][k+1]
            float b2 = P[(k + 1) * PP + lckp];  // old A[k+1][kp]
            P[(k + 1) * PP + lc1] = 0.f;  P[(k + 1) * PP + lckp] = a;
            P[kp * PP + lc1] = b2;        P[kp * PP + lckp] = 0.f;
          } else if (tid >= NF + 24 && tid < NF + 24 + mp) {
            int m = tid - (NF + 24);
            float2 a = s_tc[m][k + 1], b2 = s_tc[m][kp];
            s_tc[m][k + 1] = b2; s_tc[m][kp] = a;
          }
        } else {
          // ---- case C: trailing swap, direct snapshot writeback (live region
          // only: rows/cols < pend other than row kp's panel cells are dead) --
          if (tid >= pend && tid < NF) {
            if (tid == kp) {
              A[(size_t)kp * NF + kp] = 0.f;
            } else {
              float pvv = P[tid * PP + lc1];
              gvr = A[(size_t)tid * NF + kp];
              A[(size_t)tid * NF + kp] = pvv;
              A[(size_t)kp * NF + tid] = -pvv;
            }
          } else if (tid >= NF && tid < NF + WP) {
            int c = tid - NF;
            float old = P[kp * PP + c];
            s_oldrow[c] = old;
            P[kp * PP + c] = P[(k + 1) * PP + c];
          } else if (tid >= NF + 24 && tid < NF + 24 + mp) {
            int m = tid - (NF + 24);
            float2 a = s_tc[m][k + 1], b2 = s_tc[m][kp];
            s_tc[m][k + 1] = b2; s_tc[m][kp] = a;
          }
        }
        __syncthreads();                                  // B2
        // ---- staging (post-swap; corrections use post-swap entries) ----
        if (tid > k + 1 && tid < NF) {
          float vpost = (tid == kp) ? s_colbuf[k + 1] : vk;
          float tt = -vpost * invp;
          float cc;
          if (inpanel)        cc = P[tid * PP + lc1];
          else if (tid < pend) cc = -s_oldrow[tid - k0];
          else if (tid == kp)  cc = -s_oldrow[lc1];
          else                 cc = gvr;
          for (int m = 0; m < mp; ++m) {
            float2 ti = s_tc[m][tid], tk1 = s_tc[m][k + 1];
            cc = fmaf(ti.x, tk1.y, fmaf(-ti.y, tk1.x, cc));
          }
          s_tc[mp][tid] = make_float2(tt, cc);
        }
        __syncthreads();                                  // B3
      }
    }

    // ---- panel-end: j-outer register-cached rank-4 x2 trailing update ----
    if (pend < NF) {
      const int ty = tid >> 6, tx = tid & 63;   // 8 row streams x 64 col chunks
      const int nch = (NF - pend) >> 2;
#pragma unroll 1
      for (int g = 0; g < 2; ++g) {
        for (int jb = 0; jb < nch; jb += 64) {
          const int j4 = jb + tx;
          if (j4 < nch) {
            const int j = pend + (j4 << 2);
            float4 tj[4], cj[4];                // tau_j, c_j for 4 cols x 4 pairs
#pragma unroll
            for (int m = 0; m < 4; ++m) {
              const int mm = g * 4 + m;
              float2 a0 = s_tc[mm][j],     a1 = s_tc[mm][j + 1];
              float2 a2 = s_tc[mm][j + 2], a3 = s_tc[mm][j + 3];
              tj[m] = make_float4(a0.x, a1.x, a2.x, a3.x);
              cj[m] = make_float4(a0.y, a1.y, a2.y, a3.y);
            }
#pragma unroll 2
            for (int i = pend + ty; i < NF; i += 8) {
              float* ap = A + (size_t)i * NF + j;
              float4 a = *(float4*)ap;
#pragma unroll
              for (int m = 0; m < 4; ++m) {
                const float2 t = s_tc[g * 4 + m][i];   // (tau_i, c_i) broadcast
                a.x = fmaf(t.x, cj[m].x, fmaf(-t.y, tj[m].x, a.x));
                a.y = fmaf(t.x, cj[m].y, fmaf(-t.y, tj[m].y, a.y));
                a.z = fmaf(t.x, cj[m].z, fmaf(-t.y, tj[m].z, a.z));
                a.w = fmaf(t.x, cj[m].w, fmaf(-t.y, tj[m].w, a.w));
              }
              *(float4*)ap = a;
            }
          }
        }
      }
    }
    __syncthreads();
  }

  if (tid == 0) { out[b] = sign; out[NB + b] = logabs; }
}

extern "C" void kernel_launch(void* const* d_in, const int* in_sizes, int n_in,
                              void* d_out, int out_size, void* d_ws, size_t ws_size,
                              hipStream_t stream) {
  const float* U  = (const float*)d_in[0];
  const float* J  = (const float*)d_in[1];
  const int* idx  = (const int*)d_in[2];
  float* out = (float*)d_out;
  float* ws = (float*)d_ws;

  float* Ja  = ws;                          // 480*480
  float* Tmp = Ja + (size_t)NM * NM;        // 32*256*480
  float* Ff  = Tmp + (size_t)NB * NE * NM;  // 32*288*288

  build_ja_k<<<dim3(256), dim3(256), 0, stream>>>(J, Ja);
  gemm1_k<<<dim3(8, 4, NB), dim3(256), 0, stream>>>(U, idx, Ja, Tmp);
  gemm2_k<<<dim3(4, 4, NB), dim3(256), 0, stream>>>(U, idx, Tmp, Ff);
  fill_edges_k<<<dim3(NB), dim3(256), 0, stream>>>(U, idx, Ff);
  pfpanel_k<<<dim3(NB), dim3(512), 0, stream>>>(Ff, out);
}

// Round 13
// 467.689 us; speedup vs baseline: 1.5054x; 1.2288x over previous
//
#include <hip/hip_runtime.h>
#include <hip/hip_bf16.h>
#include <math.h>

#define NFM 512   // NFMODES
#define NE  256
#define NUN 32    // NUNPAIRED
#define NM  480   // NMODES
#define NB  32    // BATCH
#define NF  288   // NE + NUN  (Ffull dim)
#define WP  16    // panel width
#define PAIRS 8   // WP/2
#define PP  18    // panel LDS pitch (even -> float2-aligned)
#define THETA 0.03125f

typedef unsigned long long ull;

// ---------------- Ja = (J - J^T)/2 ----------------
__global__ __launch_bounds__(256)
void build_ja_k(const float* __restrict__ J, float* __restrict__ Ja) {
  int t = blockIdx.x * blockDim.x + threadIdx.x;
  int stride = gridDim.x * blockDim.x;
  for (int e = t; e < NM * NM; e += stride) {
    int i = e / NM, j = e - i * NM;
    Ja[e] = 0.5f * (J[i * NM + j] - J[j * NM + i]);
  }
}

// ---------------- Tmp[b] (256x480) = Up_b @ Ja ----------
__global__ __launch_bounds__(256)
void gemm1_k(const float* __restrict__ U, const int* __restrict__ idx,
             const float* __restrict__ Ja, float* __restrict__ Tmp) {
  const int b  = blockIdx.z;
  const int m0 = blockIdx.y << 6;
  const int n0 = blockIdx.x << 6;
  const int tid = threadIdx.x;
  __shared__ float As[16][64];
  __shared__ float Bs[16][64];
  const int ar = tid >> 2, ac = (tid & 3) << 2;
  const int br = tid >> 4, bc = (tid & 15) << 2;
  const int tx = tid & 15, ty = tid >> 4;
  const float* Arow = U + (size_t)idx[b * NE + m0 + ar] * NFM + NUN;
  float acc[4][4] = {};
  for (int l0 = 0; l0 < NM; l0 += 16) {
    float4 av = *(const float4*)(Arow + l0 + ac);
    As[ac + 0][ar] = av.x; As[ac + 1][ar] = av.y;
    As[ac + 2][ar] = av.z; As[ac + 3][ar] = av.w;
    float4 bv = make_float4(0.f, 0.f, 0.f, 0.f);
    if (n0 + bc < NM) bv = *(const float4*)(Ja + (size_t)(l0 + br) * NM + n0 + bc);
    *(float4*)(&Bs[br][bc]) = bv;
    __syncthreads();
#pragma unroll
    for (int kk = 0; kk < 16; ++kk) {
      float4 a4 = *(const float4*)(&As[kk][ty << 2]);
      float4 b4 = *(const float4*)(&Bs[kk][tx << 2]);
      float a[4] = {a4.x, a4.y, a4.z, a4.w};
      float bb[4] = {b4.x, b4.y, b4.z, b4.w};
#pragma unroll
      for (int q = 0; q < 4; ++q)
#pragma unroll
        for (int p = 0; p < 4; ++p) acc[q][p] = fmaf(a[q], bb[p], acc[q][p]);
    }
    __syncthreads();
  }
  float* Tb = Tmp + (size_t)b * NE * NM;
#pragma unroll
  for (int q = 0; q < 4; ++q) {
    int r = m0 + (ty << 2) + q;
#pragma unroll
    for (int p = 0; p < 4; ++p) {
      int m = n0 + (tx << 2) + p;
      if (m < NM) Tb[(size_t)r * NM + m] = acc[q][p];
    }
  }
}

// ---------------- F[b] = Tmp[b] @ Up_b^T  -> Ffull[0:256][0:256] ------------
__global__ __launch_bounds__(256)
void gemm2_k(const float* __restrict__ U, const int* __restrict__ idx,
             const float* __restrict__ Tmp, float* __restrict__ Ff) {
  const int b  = blockIdx.z;
  const int m0 = blockIdx.y << 6;
  const int n0 = blockIdx.x << 6;
  const int tid = threadIdx.x;
  __shared__ float As[16][64];
  __shared__ float Bs[16][64];
  const int ar = tid >> 2, ac = (tid & 3) << 2;
  const int jr = tid >> 2, kc = (tid & 3) << 2;
  const int tx = tid & 15, ty = tid >> 4;
  const float* Arow = Tmp + ((size_t)b * NE + m0 + ar) * NM;
  const float* Brow = U + (size_t)idx[b * NE + n0 + jr] * NFM + NUN;
  float acc[4][4] = {};
  for (int l0 = 0; l0 < NM; l0 += 16) {
    float4 av = *(const float4*)(Arow + l0 + ac);
    As[ac + 0][ar] = av.x; As[ac + 1][ar] = av.y;
    As[ac + 2][ar] = av.z; As[ac + 3][ar] = av.w;
    float4 bv = *(const float4*)(Brow + l0 + kc);
    Bs[kc + 0][jr] = bv.x; Bs[kc + 1][jr] = bv.y;
    Bs[kc + 2][jr] = bv.z; Bs[kc + 3][jr] = bv.w;
    __syncthreads();
#pragma unroll
    for (int kk = 0; kk < 16; ++kk) {
      float4 a4 = *(const float4*)(&As[kk][ty << 2]);
      float4 b4 = *(const float4*)(&Bs[kk][tx << 2]);
      float a[4] = {a4.x, a4.y, a4.z, a4.w};
      float bb[4] = {b4.x, b4.y, b4.z, b4.w};
#pragma unroll
      for (int q = 0; q < 4; ++q)
#pragma unroll
        for (int p = 0; p < 4; ++p) acc[q][p] = fmaf(a[q], bb[p], acc[q][p]);
    }
    __syncthreads();
  }
  float* Fb = Ff + (size_t)b * NF * NF;
#pragma unroll
  for (int q = 0; q < 4; ++q) {
    int i = m0 + (ty << 2) + q;
#pragma unroll
    for (int p = 0; p < 4; ++p) {
      int j = n0 + (tx << 2) + p;
      Fb[(size_t)i * NF + j] = acc[q][p];
    }
  }
}

// ---------------- edges ---------------
__global__ __launch_bounds__(256)
void fill_edges_k(const float* __restrict__ U, const int* __restrict__ idx,
                  float* __restrict__ Ff) {
  const int b = blockIdx.x;
  const int tid = threadIdx.x;
  float* Fb = Ff + (size_t)b * NF * NF;
  const int gr = idx[b * NE + tid];
#pragma unroll 4
  for (int u = 0; u < NUN; ++u) {
    float v = U[(size_t)gr * NFM + u];
    Fb[(size_t)tid * NF + NE + u] = v;
    Fb[(size_t)(NE + u) * NF + tid] = -v;
  }
  if (tid < NUN) {
    for (int v = 0; v < NUN; ++v) Fb[(size_t)(NE + tid) * NF + NE + v] = 0.f;
  }
}

// ---------------- Pfaffian: blocked Parlett-Reid, threshold pivoting --------
// Round-6 factor structure verbatim (measured best): float2 s_tc (tau
// pre-scaled, c raw), 2-barrier common step, 3-barrier rare swap steps.
// Trailing pass: SINGLE j-outer pass, all 8 pairs register-cached
// (tj[8]/cj[8]), i-inner streaming with broadcast (tau_i,c_i) reads —
// one global RMW pass AND no per-row coefficient re-reads.
__global__ __launch_bounds__(512)
void pfpanel_k(float* __restrict__ Ff, float* __restrict__ out) {
  const int b = blockIdx.x;
  float* __restrict__ A = Ff + (size_t)b * NF * NF;
  const int tid = threadIdx.x;
  __shared__ __align__(16) float P[NF * PP];
  __shared__ __align__(16) float2 s_tc[PAIRS][NF];   // (tau, c) interleaved
  __shared__ __align__(16) float s_colbuf[NF];
  __shared__ float s_oldrow[WP];
  __shared__ ull s_red[8];

  float sign = 1.f, logabs = 0.f;   // thread 0 only

#pragma unroll 1
  for (int k0 = 0; k0 < NF; k0 += WP) {
    const int pend = k0 + WP;

    // ---- panel load: P[r][0..15] = A[r][k0..k0+15] ----
    for (int e = tid; e < NF * 4; e += 512) {
      int r = e >> 2, c4 = (e & 3) << 2;
      float4 v = *(const float4*)(A + (size_t)r * NF + k0 + c4);
      float2* d = (float2*)&P[r * PP + c4];
      d[0] = make_float2(v.x, v.y);
      d[1] = make_float2(v.z, v.w);
    }
    __syncthreads();

#pragma unroll 1
    for (int mp = 0; mp < PAIRS; ++mp) {
      const int k = k0 + 2 * mp, lc = 2 * mp, lc1 = lc + 1;

      // ---- phase 1: both pair columns + corrections (registers) + max -----
      float vk = 0.f, vk1 = 0.f;
      ull pk = 0;
      if (tid > k && tid < NF) {
        float2 pv = *(const float2*)&P[tid * PP + lc];
        vk = pv.x; vk1 = pv.y;
        for (int m = 0; m < mp; ++m) {
          float2 ti  = s_tc[m][tid];
          float2 tk  = s_tc[m][k];
          float2 tk1 = s_tc[m][k + 1];
          vk  = fmaf(ti.x, tk.y,  fmaf(-ti.y, tk.x,  vk));
          vk1 = fmaf(ti.x, tk1.y, fmaf(-ti.y, tk1.x, vk1));
        }
        s_colbuf[tid] = vk;
        pk = ((ull)__float_as_uint(fabsf(vk)) << 32) | (ull)(NF - tid);
      }
#pragma unroll
      for (int m = 32; m > 0; m >>= 1) {
        ull o = __shfl_xor(pk, m, 64);
        if (o > pk) pk = o;
      }
      if ((tid & 63) == 0) s_red[tid >> 6] = pk;
      __syncthreads();                                    // B1
      ull best = s_red[0];
#pragma unroll
      for (int w = 1; w < 8; ++w) if (s_red[w] > best) best = s_red[w];
      const float vmax = __uint_as_float((unsigned)(best >> 32));
      const float pivdef = -s_colbuf[k + 1];
      const bool doswap = fabsf(pivdef) < THETA * vmax;
      const int kp = doswap ? (NF - (int)(best & 0xffffffffULL)) : (k + 1);
      const float pivot = doswap ? -s_colbuf[kp] : pivdef;
      const float invp = 1.f / pivot;
      if (tid == 0) {
        if (kp != k + 1) sign = -sign;
        sign *= (pivot > 0.f ? 1.f : (pivot < 0.f ? -1.f : 0.f));
        logabs += logf(fabsf(pivot));
      }

      if (!doswap) {
        // ================= common path: no swap, stage from registers ======
        if (tid > k + 1 && tid < NF)
          s_tc[mp][tid] = make_float2(-vk * invp, vk1);
        __syncthreads();                                  // B2
      } else {
        const bool inpanel = (kp < pend);
        float gvr = 0.f;
        if (inpanel) {
          // ---- case B: in-panel swap ----
          const int lckp = kp - k0;
          if (tid > k + 1 && tid < NF && tid != kp) {
            float a = P[tid * PP + lc1], b2 = P[tid * PP + lckp];
            P[tid * PP + lc1] = b2; P[tid * PP + lckp] = a;
          } else if (tid >= NF && tid < NF + WP) {
            int c = tid - NF;
            if (c != lc1 && c != lckp) {
              float a = P[(k + 1) * PP + c], b2 = P[kp * PP + c];
              P[(k + 1) * PP + c] = b2; P[kp * PP + c] = a;
            }
          } else if (tid == NF + WP) {
            float a = P[kp * PP + lc1];         // old A[kp][k+1]
            float b2 = P[(k + 1) * PP + lckp];  // old A[k+1][kp]
            P[(k + 1) * PP + lc1] = 0.f;  P[(k + 1) * PP + lckp] = a;
            P[kp * PP + lc1] = b2;        P[kp * PP + lckp] = 0.f;
          } else if (tid >= NF + 24 && tid < NF + 24 + mp) {
            int m = tid - (NF + 24);
            float2 a = s_tc[m][k + 1], b2 = s_tc[m][kp];
            s_tc[m][k + 1] = b2; s_tc[m][kp] = a;
          }
        } else {
          // ---- case C: trailing swap, direct snapshot writeback (live region
          // only: rows/cols < pend other than row kp's panel cells are dead) --
          if (tid >= pend && tid < NF) {
            if (tid == kp) {
              A[(size_t)kp * NF + kp] = 0.f;
            } else {
              float pvv = P[tid * PP + lc1];
              gvr = A[(size_t)tid * NF + kp];
              A[(size_t)tid * NF + kp] = pvv;
              A[(size_t)kp * NF + tid] = -pvv;
            }
          } else if (tid >= NF && tid < NF + WP) {
            int c = tid - NF;
            float old = P[kp * PP + c];
            s_oldrow[c] = old;
            P[kp * PP + c] = P[(k + 1) * PP + c];
          } else if (tid >= NF + 24 && tid < NF + 24 + mp) {
            int m = tid - (NF + 24);
            float2 a = s_tc[m][k + 1], b2 = s_tc[m][kp];
            s_tc[m][k + 1] = b2; s_tc[m][kp] = a;
          }
        }
        __syncthreads();                                  // B2
        // ---- staging (post-swap; corrections use post-swap entries) ----
        if (tid > k + 1 && tid < NF) {
          float vpost = (tid == kp) ? s_colbuf[k + 1] : vk;
          float tt = -vpost * invp;
          float cc;
          if (inpanel)        cc = P[tid * PP + lc1];
          else if (tid < pend) cc = -s_oldrow[tid - k0];
          else if (tid == kp)  cc = -s_oldrow[lc1];
          else                 cc = gvr;
          for (int m = 0; m < mp; ++m) {
            float2 ti = s_tc[m][tid], tk1 = s_tc[m][k + 1];
            cc = fmaf(ti.x, tk1.y, fmaf(-ti.y, tk1.x, cc));
          }
          s_tc[mp][tid] = make_float2(tt, cc);
        }
        __syncthreads();                                  // B3
      }
    }

    // ---- panel-end: SINGLE-PASS j-outer trailing update, all 8 pairs ------
    if (pend < NF) {
      const int ty = tid >> 6, tx = tid & 63;   // 8 row streams x 64 col chunks
      const int nch = (NF - pend) >> 2;
      for (int jb = 0; jb < nch; jb += 64) {
        const int j4 = jb + tx;
        if (j4 < nch) {
          const int j = pend + (j4 << 2);
          float4 tj[PAIRS], cj[PAIRS];   // tau_j, c_j: 4 cols x 8 pairs = 64 VGPR
#pragma unroll
          for (int m = 0; m < PAIRS; ++m) {
            float4 q0 = *(const float4*)(&s_tc[m][j]);       // t,c,t,c
            float4 q1 = *(const float4*)(&s_tc[m][j + 2]);
            tj[m] = make_float4(q0.x, q0.z, q1.x, q1.z);
            cj[m] = make_float4(q0.y, q0.w, q1.y, q1.w);
          }
#pragma unroll 2
          for (int i = pend + ty; i < NF; i += 8) {
            float* ap = A + (size_t)i * NF + j;
            float4 a = *(float4*)ap;
#pragma unroll
            for (int m = 0; m < PAIRS; ++m) {
              const float2 t = s_tc[m][i];   // (tau_i, c_i) broadcast
              a.x = fmaf(t.x, cj[m].x, fmaf(-t.y, tj[m].x, a.x));
              a.y = fmaf(t.x, cj[m].y, fmaf(-t.y, tj[m].y, a.y));
              a.z = fmaf(t.x, cj[m].z, fmaf(-t.y, tj[m].z, a.z));
              a.w = fmaf(t.x, cj[m].w, fmaf(-t.y, tj[m].w, a.w));
            }
            *(float4*)ap = a;
          }
        }
      }
    }
    __syncthreads();
  }

  if (tid == 0) { out[b] = sign; out[NB + b] = logabs; }
}

extern "C" void kernel_launch(void* const* d_in, const int* in_sizes, int n_in,
                              void* d_out, int out_size, void* d_ws, size_t ws_size,
                              hipStream_t stream) {
  const float* U  = (const float*)d_in[0];
  const float* J  = (const float*)d_in[1];
  const int* idx  = (const int*)d_in[2];
  float* out = (float*)d_out;
  float* ws = (float*)d_ws;

  float* Ja  = ws;                          // 480*480
  float* Tmp = Ja + (size_t)NM * NM;        // 32*256*480
  float* Ff  = Tmp + (size_t)NB * NE * NM;  // 32*288*288

  build_ja_k<<<dim3(256), dim3(256), 0, stream>>>(J, Ja);
  gemm1_k<<<dim3(8, 4, NB), dim3(256), 0, stream>>>(U, idx, Ja, Tmp);
  gemm2_k<<<dim3(4, 4, NB), dim3(256), 0, stream>>>(U, idx, Tmp, Ff);
  fill_edges_k<<<dim3(NB), dim3(256), 0, stream>>>(U, idx, Ff);
  pfpanel_k<<<dim3(NB), dim3(512), 0, stream>>>(Ff, out);
}

// Round 14
// 445.912 us; speedup vs baseline: 1.5789x; 1.0488x over previous
//
#include <hip/hip_runtime.h>
#include <hip/hip_bf16.h>
#include <math.h>

#define NFM 512   // NFMODES
#define NE  256
#define NUN 32    // NUNPAIRED
#define NM  480   // NMODES
#define NB  32    // BATCH
#define NF  288   // NE + NUN  (Ffull dim)
#define WP  16    // panel width
#define PAIRS 8   // WP/2
#define PP  18    // panel LDS pitch (even -> float2-aligned)
#define THETA 0.03125f

typedef unsigned long long ull;

// ---------------- Ja = (J - J^T)/2 ----------------
__global__ __launch_bounds__(256)
void build_ja_k(const float* __restrict__ J, float* __restrict__ Ja) {
  int t = blockIdx.x * blockDim.x + threadIdx.x;
  int stride = gridDim.x * blockDim.x;
  for (int e = t; e < NM * NM; e += stride) {
    int i = e / NM, j = e - i * NM;
    Ja[e] = 0.5f * (J[i * NM + j] - J[j * NM + i]);
  }
}

// ---------------- Tmp[b] (256x480) = Up_b @ Ja ----------
__global__ __launch_bounds__(256)
void gemm1_k(const float* __restrict__ U, const int* __restrict__ idx,
             const float* __restrict__ Ja, float* __restrict__ Tmp) {
  const int b  = blockIdx.z;
  const int m0 = blockIdx.y << 6;
  const int n0 = blockIdx.x << 6;
  const int tid = threadIdx.x;
  __shared__ float As[16][64];
  __shared__ float Bs[16][64];
  const int ar = tid >> 2, ac = (tid & 3) << 2;
  const int br = tid >> 4, bc = (tid & 15) << 2;
  const int tx = tid & 15, ty = tid >> 4;
  const float* Arow = U + (size_t)idx[b * NE + m0 + ar] * NFM + NUN;
  float acc[4][4] = {};
  for (int l0 = 0; l0 < NM; l0 += 16) {
    float4 av = *(const float4*)(Arow + l0 + ac);
    As[ac + 0][ar] = av.x; As[ac + 1][ar] = av.y;
    As[ac + 2][ar] = av.z; As[ac + 3][ar] = av.w;
    float4 bv = make_float4(0.f, 0.f, 0.f, 0.f);
    if (n0 + bc < NM) bv = *(const float4*)(Ja + (size_t)(l0 + br) * NM + n0 + bc);
    *(float4*)(&Bs[br][bc]) = bv;
    __syncthreads();
#pragma unroll
    for (int kk = 0; kk < 16; ++kk) {
      float4 a4 = *(const float4*)(&As[kk][ty << 2]);
      float4 b4 = *(const float4*)(&Bs[kk][tx << 2]);
      float a[4] = {a4.x, a4.y, a4.z, a4.w};
      float bb[4] = {b4.x, b4.y, b4.z, b4.w};
#pragma unroll
      for (int q = 0; q < 4; ++q)
#pragma unroll
        for (int p = 0; p < 4; ++p) acc[q][p] = fmaf(a[q], bb[p], acc[q][p]);
    }
    __syncthreads();
  }
  float* Tb = Tmp + (size_t)b * NE * NM;
#pragma unroll
  for (int q = 0; q < 4; ++q) {
    int r = m0 + (ty << 2) + q;
#pragma unroll
    for (int p = 0; p < 4; ++p) {
      int m = n0 + (tx << 2) + p;
      if (m < NM) Tb[(size_t)r * NM + m] = acc[q][p];
    }
  }
}

// ---------------- F[b] = Tmp[b] @ Up_b^T  -> Ffull[0:256][0:256] ------------
__global__ __launch_bounds__(256)
void gemm2_k(const float* __restrict__ U, const int* __restrict__ idx,
             const float* __restrict__ Tmp, float* __restrict__ Ff) {
  const int b  = blockIdx.z;
  const int m0 = blockIdx.y << 6;
  const int n0 = blockIdx.x << 6;
  const int tid = threadIdx.x;
  __shared__ float As[16][64];
  __shared__ float Bs[16][64];
  const int ar = tid >> 2, ac = (tid & 3) << 2;
  const int jr = tid >> 2, kc = (tid & 3) << 2;
  const int tx = tid & 15, ty = tid >> 4;
  const float* Arow = Tmp + ((size_t)b * NE + m0 + ar) * NM;
  const float* Brow = U + (size_t)idx[b * NE + n0 + jr] * NFM + NUN;
  float acc[4][4] = {};
  for (int l0 = 0; l0 < NM; l0 += 16) {
    float4 av = *(const float4*)(Arow + l0 + ac);
    As[ac + 0][ar] = av.x; As[ac + 1][ar] = av.y;
    As[ac + 2][ar] = av.z; As[ac + 3][ar] = av.w;
    float4 bv = *(const float4*)(Brow + l0 + kc);
    Bs[kc + 0][jr] = bv.x; Bs[kc + 1][jr] = bv.y;
    Bs[kc + 2][jr] = bv.z; Bs[kc + 3][jr] = bv.w;
    __syncthreads();
#pragma unroll
    for (int kk = 0; kk < 16; ++kk) {
      float4 a4 = *(const float4*)(&As[kk][ty << 2]);
      float4 b4 = *(const float4*)(&Bs[kk][tx << 2]);
      float a[4] = {a4.x, a4.y, a4.z, a4.w};
      float bb[4] = {b4.x, b4.y, b4.z, b4.w};
#pragma unroll
      for (int q = 0; q < 4; ++q)
#pragma unroll
        for (int p = 0; p < 4; ++p) acc[q][p] = fmaf(a[q], bb[p], acc[q][p]);
    }
    __syncthreads();
  }
  float* Fb = Ff + (size_t)b * NF * NF;
#pragma unroll
  for (int q = 0; q < 4; ++q) {
    int i = m0 + (ty << 2) + q;
#pragma unroll
    for (int p = 0; p < 4; ++p) {
      int j = n0 + (tx << 2) + p;
      Fb[(size_t)i * NF + j] = acc[q][p];
    }
  }
}

// ---------------- edges ---------------
__global__ __launch_bounds__(256)
void fill_edges_k(const float* __restrict__ U, const int* __restrict__ idx,
                  float* __restrict__ Ff) {
  const int b = blockIdx.x;
  const int tid = threadIdx.x;
  float* Fb = Ff + (size_t)b * NF * NF;
  const int gr = idx[b * NE + tid];
#pragma unroll 4
  for (int u = 0; u < NUN; ++u) {
    float v = U[(size_t)gr * NFM + u];
    Fb[(size_t)tid * NF + NE + u] = v;
    Fb[(size_t)(NE + u) * NF + tid] = -v;
  }
  if (tid < NUN) {
    for (int v = 0; v < NUN; ++v) Fb[(size_t)(NE + tid) * NF + NE + v] = 0.f;
  }
}

// ---------------- Pfaffian: blocked Parlett-Reid, threshold pivoting --------
// R13 algebra with a 1-BARRIER common step: s_tc stores RAW (nu=-colk, c);
// consumers fold iv from s_invp (benign same-value write by all threads).
// Speculative stage + pivdef slot + 32-bit packed argmax pre-B1; post-B1 is
// uniform decide only. Parity buffers (s_pivdef/s_redu) make the 1-barrier
// pipeline WAR-safe (reuse distance = 2 steps >= 2 barriers).
// Swap steps (rare): R13-verified paths, restaged raw, +2 barriers.
__global__ __launch_bounds__(512)
void pfpanel_k(float* __restrict__ Ff, float* __restrict__ out) {
  const int b = blockIdx.x;
  float* __restrict__ A = Ff + (size_t)b * NF * NF;
  const int tid = threadIdx.x;
  __shared__ __align__(16) float P[NF * PP];
  __shared__ __align__(16) float2 s_tc[PAIRS][NF];   // (nu, c) RAW
  __shared__ __align__(16) float s_colbuf[NF];
  __shared__ float s_oldrow[WP];
  __shared__ float s_pivdef[2];
  __shared__ float s_invp[PAIRS];
  __shared__ __align__(16) unsigned s_redu[2][8];

  float sign = 1.f, logabs = 0.f;   // thread 0 only

#pragma unroll 1
  for (int k0 = 0; k0 < NF; k0 += WP) {
    const int pend = k0 + WP;

    // ---- panel load: P[r][0..15] = A[r][k0..k0+15] ----
    for (int e = tid; e < NF * 4; e += 512) {
      int r = e >> 2, c4 = (e & 3) << 2;
      float4 v = *(const float4*)(A + (size_t)r * NF + k0 + c4);
      float2* d = (float2*)&P[r * PP + c4];
      d[0] = make_float2(v.x, v.y);
      d[1] = make_float2(v.z, v.w);
    }
    __syncthreads();

#pragma unroll 1
    for (int mp = 0; mp < PAIRS; ++mp) {
      const int k = k0 + 2 * mp, lc = 2 * mp, lc1 = lc + 1;
      const int par = mp & 1;

      // ---- phase 1: pair cols + iv-folded corrections; spec stage; argmax -
      float vk = 0.f, vk1 = 0.f;
      unsigned pk = 0;
      if (tid > k && tid < NF) {
        float2 pv = *(const float2*)&P[tid * PP + lc];
        vk = pv.x; vk1 = pv.y;
#pragma unroll 1
        for (int m = 0; m < mp; ++m) {
          const float im = s_invp[m];
          float2 ti  = s_tc[m][tid];
          float2 tk  = s_tc[m][k];
          float2 tk1 = s_tc[m][k + 1];
          vk  = fmaf(ti.x, im * tk.y,  fmaf(-ti.y, im * tk.x,  vk));
          vk1 = fmaf(ti.x, im * tk1.y, fmaf(-ti.y, im * tk1.x, vk1));
        }
        s_colbuf[tid] = vk;
        if (tid > k + 1) s_tc[mp][tid] = make_float2(-vk, vk1);  // spec, RAW
        else             s_pivdef[par] = vk;                     // tid == k+1
        pk = (__float_as_uint(fabsf(vk)) & 0xFFFFFE00u) | (unsigned)tid;
      }
#pragma unroll
      for (int s = 32; s > 0; s >>= 1) {
        unsigned o = (unsigned)__shfl_xor((int)pk, s, 64);
        if (o > pk) pk = o;
      }
      if ((tid & 63) == 0) s_redu[par][tid >> 6] = pk;
      __syncthreads();                                    // B1 (only barrier)
      uint4 r0 = *(const uint4*)&s_redu[par][0];
      uint4 r1 = *(const uint4*)&s_redu[par][4];
      unsigned best = r0.x;
      best = best > r0.y ? best : r0.y;
      best = best > r0.z ? best : r0.z;
      best = best > r0.w ? best : r0.w;
      best = best > r1.x ? best : r1.x;
      best = best > r1.y ? best : r1.y;
      best = best > r1.z ? best : r1.z;
      best = best > r1.w ? best : r1.w;
      const float vmax = __uint_as_float(best & 0xFFFFFE00u);
      const float pivdef = -s_pivdef[par];
      const bool doswap = fabsf(pivdef) < THETA * vmax;
      const int kp = doswap ? (int)(best & 0x1FFu) : (k + 1);
      const float pivot = doswap ? -s_colbuf[kp] : pivdef;
      const float invp = 1.f / pivot;
      s_invp[mp] = invp;   // all threads write identical value (benign)
      if (tid == 0) {
        if (doswap) sign = -sign;
        sign *= (pivot > 0.f ? 1.f : (pivot < 0.f ? -1.f : 0.f));
        logabs += logf(fabsf(pivot));
      }

      if (doswap) {
        const bool inpanel = (kp < pend);
        float gvr = 0.f;
        if (inpanel) {
          // ---- case B: in-panel swap ----
          const int lckp = kp - k0;
          if (tid > k + 1 && tid < NF && tid != kp) {
            float a = P[tid * PP + lc1], b2 = P[tid * PP + lckp];
            P[tid * PP + lc1] = b2; P[tid * PP + lckp] = a;
          } else if (tid >= NF && tid < NF + WP) {
            int c = tid - NF;
            if (c != lc1 && c != lckp) {
              float a = P[(k + 1) * PP + c], b2 = P[kp * PP + c];
              P[(k + 1) * PP + c] = b2; P[kp * PP + c] = a;
            }
          } else if (tid == NF + WP) {
            float a = P[kp * PP + lc1];         // old A[kp][k+1]
            float b2 = P[(k + 1) * PP + lckp];  // old A[k+1][kp]
            P[(k + 1) * PP + lc1] = 0.f;  P[(k + 1) * PP + lckp] = a;
            P[kp * PP + lc1] = b2;        P[kp * PP + lckp] = 0.f;
          } else if (tid >= NF + 24 && tid < NF + 24 + mp) {
            int m = tid - (NF + 24);
            float2 a = s_tc[m][k + 1], b2 = s_tc[m][kp];
            s_tc[m][k + 1] = b2; s_tc[m][kp] = a;
          }
        } else {
          // ---- case C: trailing swap, snapshot-consistent writeback ----
          if (tid >= pend && tid < NF) {
            if (tid == kp) {
              A[(size_t)kp * NF + kp] = 0.f;
            } else {
              float pvv = P[tid * PP + lc1];
              gvr = A[(size_t)tid * NF + kp];
              A[(size_t)tid * NF + kp] = pvv;
              A[(size_t)kp * NF + tid] = -pvv;
            }
          } else if (tid >= NF && tid < NF + WP) {
            int c = tid - NF;
            float old = P[kp * PP + c];
            s_oldrow[c] = old;
            P[kp * PP + c] = P[(k + 1) * PP + c];
          } else if (tid >= NF + 24 && tid < NF + 24 + mp) {
            int m = tid - (NF + 24);
            float2 a = s_tc[m][k + 1], b2 = s_tc[m][kp];
            s_tc[m][k + 1] = b2; s_tc[m][kp] = a;
          }
        }
        __syncthreads();                                  // B2
        // ---- restage (post-swap; corrections iv-folded, post-swap entries) -
        if (tid > k + 1 && tid < NF) {
          float vpost = (tid == kp) ? s_colbuf[k + 1] : vk;
          float cc;
          if (inpanel)        cc = P[tid * PP + lc1];
          else if (tid < pend) cc = -s_oldrow[tid - k0];
          else if (tid == kp)  cc = -s_oldrow[lc1];
          else                 cc = gvr;
#pragma unroll 1
          for (int m = 0; m < mp; ++m) {
            const float im = s_invp[m];
            float2 ti = s_tc[m][tid], tk1 = s_tc[m][k + 1];
            cc = fmaf(ti.x, im * tk1.y, fmaf(-ti.y, im * tk1.x, cc));
          }
          s_tc[mp][tid] = make_float2(-vpost, cc);        // RAW
        }
        __syncthreads();                                  // B3
      }
    }
    __syncthreads();   // all pairs staged + swap-path P reads done

    // ---- panel-end: SINGLE-PASS j-outer trailing, iv folded into cache ----
    if (pend < NF) {
      const int ty = tid >> 6, tx = tid & 63;   // 8 row streams x 64 col chunks
      const int nch = (NF - pend) >> 2;
      float ivr[PAIRS];
#pragma unroll
      for (int m = 0; m < PAIRS; ++m) ivr[m] = s_invp[m];
      for (int jb = 0; jb < nch; jb += 64) {
        const int j4 = jb + tx;
        if (j4 < nch) {
          const int j = pend + (j4 << 2);
          float4 tj[PAIRS], cj[PAIRS];   // iv*nu_j, iv*c_j: 4 cols x 8 pairs
#pragma unroll
          for (int m = 0; m < PAIRS; ++m) {
            const float im = ivr[m];
            float4 q0 = *(const float4*)(&s_tc[m][j]);       // nu,c,nu,c
            float4 q1 = *(const float4*)(&s_tc[m][j + 2]);
            tj[m] = make_float4(q0.x * im, q0.z * im, q1.x * im, q1.z * im);
            cj[m] = make_float4(q0.y * im, q0.w * im, q1.y * im, q1.w * im);
          }
#pragma unroll 2
          for (int i = pend + ty; i < NF; i += 8) {
            float* ap = A + (size_t)i * NF + j;
            float4 a = *(float4*)ap;
#pragma unroll
            for (int m = 0; m < PAIRS; ++m) {
              const float2 t = s_tc[m][i];   // (nu_i, c_i) broadcast
              a.x = fmaf(t.x, cj[m].x, fmaf(-t.y, tj[m].x, a.x));
              a.y = fmaf(t.x, cj[m].y, fmaf(-t.y, tj[m].y, a.y));
              a.z = fmaf(t.x, cj[m].z, fmaf(-t.y, tj[m].z, a.z));
              a.w = fmaf(t.x, cj[m].w, fmaf(-t.y, tj[m].w, a.w));
            }
            *(float4*)ap = a;
          }
        }
      }
    }
    __syncthreads();
  }

  if (tid == 0) { out[b] = sign; out[NB + b] = logabs; }
}

extern "C" void kernel_launch(void* const* d_in, const int* in_sizes, int n_in,
                              void* d_out, int out_size, void* d_ws, size_t ws_size,
                              hipStream_t stream) {
  const float* U  = (const float*)d_in[0];
  const float* J  = (const float*)d_in[1];
  const int* idx  = (const int*)d_in[2];
  float* out = (float*)d_out;
  float* ws = (float*)d_ws;

  float* Ja  = ws;                          // 480*480
  float* Tmp = Ja + (size_t)NM * NM;        // 32*256*480
  float* Ff  = Tmp + (size_t)NB * NE * NM;  // 32*288*288

  build_ja_k<<<dim3(256), dim3(256), 0, stream>>>(J, Ja);
  gemm1_k<<<dim3(8, 4, NB), dim3(256), 0, stream>>>(U, idx, Ja, Tmp);
  gemm2_k<<<dim3(4, 4, NB), dim3(256), 0, stream>>>(U, idx, Tmp, Ff);
  fill_edges_k<<<dim3(NB), dim3(256), 0, stream>>>(U, idx, Ff);
  pfpanel_k<<<dim3(NB), dim3(512), 0, stream>>>(Ff, out);
}

// Round 15
// 353.953 us; speedup vs baseline: 1.9891x; 1.2598x over previous
//
#include <hip/hip_runtime.h>
#include <hip/hip_bf16.h>
#include <math.h>

#define NFM 512   // NFMODES
#define NE  256
#define NUN 32    // NUNPAIRED
#define NM  480   // NMODES
#define NB  32    // BATCH
#define NF  288   // NE + NUN  (Ffull dim)
#define WP  16    // panel width
#define PAIRS 8   // WP/2
#define PP  18    // panel LDS pitch (even -> float2-aligned)
#define THETA 0.03125f

typedef unsigned long long ull;

// ---------------- Ja = (J - J^T)/2 ----------------
__global__ __launch_bounds__(256)
void build_ja_k(const float* __restrict__ J, float* __restrict__ Ja) {
  int t = blockIdx.x * blockDim.x + threadIdx.x;
  int stride = gridDim.x * blockDim.x;
  for (int e = t; e < NM * NM; e += stride) {
    int i = e / NM, j = e - i * NM;
    Ja[e] = 0.5f * (J[i * NM + j] - J[j * NM + i]);
  }
}

// ---------------- Tmp[b] (256x480) = Up_b @ Ja ----------
__global__ __launch_bounds__(256)
void gemm1_k(const float* __restrict__ U, const int* __restrict__ idx,
             const float* __restrict__ Ja, float* __restrict__ Tmp) {
  const int b  = blockIdx.z;
  const int m0 = blockIdx.y << 6;
  const int n0 = blockIdx.x << 6;
  const int tid = threadIdx.x;
  __shared__ float As[16][64];
  __shared__ float Bs[16][64];
  const int ar = tid >> 2, ac = (tid & 3) << 2;
  const int br = tid >> 4, bc = (tid & 15) << 2;
  const int tx = tid & 15, ty = tid >> 4;
  const float* Arow = U + (size_t)idx[b * NE + m0 + ar] * NFM + NUN;
  float acc[4][4] = {};
  for (int l0 = 0; l0 < NM; l0 += 16) {
    float4 av = *(const float4*)(Arow + l0 + ac);
    As[ac + 0][ar] = av.x; As[ac + 1][ar] = av.y;
    As[ac + 2][ar] = av.z; As[ac + 3][ar] = av.w;
    float4 bv = make_float4(0.f, 0.f, 0.f, 0.f);
    if (n0 + bc < NM) bv = *(const float4*)(Ja + (size_t)(l0 + br) * NM + n0 + bc);
    *(float4*)(&Bs[br][bc]) = bv;
    __syncthreads();
#pragma unroll
    for (int kk = 0; kk < 16; ++kk) {
      float4 a4 = *(const float4*)(&As[kk][ty << 2]);
      float4 b4 = *(const float4*)(&Bs[kk][tx << 2]);
      float a[4] = {a4.x, a4.y, a4.z, a4.w};
      float bb[4] = {b4.x, b4.y, b4.z, b4.w};
#pragma unroll
      for (int q = 0; q < 4; ++q)
#pragma unroll
        for (int p = 0; p < 4; ++p) acc[q][p] = fmaf(a[q], bb[p], acc[q][p]);
    }
    __syncthreads();
  }
  float* Tb = Tmp + (size_t)b * NE * NM;
#pragma unroll
  for (int q = 0; q < 4; ++q) {
    int r = m0 + (ty << 2) + q;
#pragma unroll
    for (int p = 0; p < 4; ++p) {
      int m = n0 + (tx << 2) + p;
      if (m < NM) Tb[(size_t)r * NM + m] = acc[q][p];
    }
  }
}

// ---------------- F[b] = Tmp[b] @ Up_b^T  -> Ffull[0:256][0:256] ------------
__global__ __launch_bounds__(256)
void gemm2_k(const float* __restrict__ U, const int* __restrict__ idx,
             const float* __restrict__ Tmp, float* __restrict__ Ff) {
  const int b  = blockIdx.z;
  const int m0 = blockIdx.y << 6;
  const int n0 = blockIdx.x << 6;
  const int tid = threadIdx.x;
  __shared__ float As[16][64];
  __shared__ float Bs[16][64];
  const int ar = tid >> 2, ac = (tid & 3) << 2;
  const int jr = tid >> 2, kc = (tid & 3) << 2;
  const int tx = tid & 15, ty = tid >> 4;
  const float* Arow = Tmp + ((size_t)b * NE + m0 + ar) * NM;
  const float* Brow = U + (size_t)idx[b * NE + n0 + jr] * NFM + NUN;
  float acc[4][4] = {};
  for (int l0 = 0; l0 < NM; l0 += 16) {
    float4 av = *(const float4*)(Arow + l0 + ac);
    As[ac + 0][ar] = av.x; As[ac + 1][ar] = av.y;
    As[ac + 2][ar] = av.z; As[ac + 3][ar] = av.w;
    float4 bv = *(const float4*)(Brow + l0 + kc);
    Bs[kc + 0][jr] = bv.x; Bs[kc + 1][jr] = bv.y;
    Bs[kc + 2][jr] = bv.z; Bs[kc + 3][jr] = bv.w;
    __syncthreads();
#pragma unroll
    for (int kk = 0; kk < 16; ++kk) {
      float4 a4 = *(const float4*)(&As[kk][ty << 2]);
      float4 b4 = *(const float4*)(&Bs[kk][tx << 2]);
      float a[4] = {a4.x, a4.y, a4.z, a4.w};
      float bb[4] = {b4.x, b4.y, b4.z, b4.w};
#pragma unroll
      for (int q = 0; q < 4; ++q)
#pragma unroll
        for (int p = 0; p < 4; ++p) acc[q][p] = fmaf(a[q], bb[p], acc[q][p]);
    }
    __syncthreads();
  }
  float* Fb = Ff + (size_t)b * NF * NF;
#pragma unroll
  for (int q = 0; q < 4; ++q) {
    int i = m0 + (ty << 2) + q;
#pragma unroll
    for (int p = 0; p < 4; ++p) {
      int j = n0 + (tx << 2) + p;
      Fb[(size_t)i * NF + j] = acc[q][p];
    }
  }
}

// ---------------- edges ---------------
__global__ __launch_bounds__(256)
void fill_edges_k(const float* __restrict__ U, const int* __restrict__ idx,
                  float* __restrict__ Ff) {
  const int b = blockIdx.x;
  const int tid = threadIdx.x;
  float* Fb = Ff + (size_t)b * NF * NF;
  const int gr = idx[b * NE + tid];
#pragma unroll 4
  for (int u = 0; u < NUN; ++u) {
    float v = U[(size_t)gr * NFM + u];
    Fb[(size_t)tid * NF + NE + u] = v;
    Fb[(size_t)(NE + u) * NF + tid] = -v;
  }
  if (tid < NUN) {
    for (int v = 0; v < NUN; ++v) Fb[(size_t)(NE + tid) * NF + NE + v] = 0.f;
  }
}

// ---------------- Pfaffian: blocked Parlett-Reid, threshold pivoting --------
// R14 base (1-barrier common step, raw (nu,c) staging, iv in s_invp) plus:
//  (1) fixed-count UNROLLED correction loop with register masking
//      ((m<mp)?d:0 via cndmask — garbage-safe) -> pipelined LDS loads;
//  (2) branchy pivot decide -> no s_colbuf[kp] load on the common path;
//  (3) next-panel P staging folded into the trailing pass (registers->LDS),
//      explicit panel load only at k0==0.
__global__ __launch_bounds__(512)
void pfpanel_k(float* __restrict__ Ff, float* __restrict__ out) {
  const int b = blockIdx.x;
  float* __restrict__ A = Ff + (size_t)b * NF * NF;
  const int tid = threadIdx.x;
  __shared__ __align__(16) float P[NF * PP];
  __shared__ __align__(16) float2 s_tc[PAIRS][NF];   // (nu, c) RAW
  __shared__ __align__(16) float s_colbuf[NF];
  __shared__ float s_oldrow[WP];
  __shared__ float s_pivdef[2];
  __shared__ float s_invp[PAIRS];
  __shared__ __align__(16) unsigned s_redu[2][8];

  float sign = 1.f, logabs = 0.f;   // thread 0 only

#pragma unroll 1
  for (int k0 = 0; k0 < NF; k0 += WP) {
    const int pend = k0 + WP;

    if (k0 == 0) {
      // ---- first-panel load: P[r][0..15] = A[r][0..15] ----
      for (int e = tid; e < NF * 4; e += 512) {
        int r = e >> 2, c4 = (e & 3) << 2;
        float4 v = *(const float4*)(A + (size_t)r * NF + c4);
        float2* d = (float2*)&P[r * PP + c4];
        d[0] = make_float2(v.x, v.y);
        d[1] = make_float2(v.z, v.w);
      }
      __syncthreads();
    }
    // (for k0>0, P was staged by the previous panel's trailing pass)

#pragma unroll 1
    for (int mp = 0; mp < PAIRS; ++mp) {
      const int k = k0 + 2 * mp, lc = 2 * mp, lc1 = lc + 1;
      const int par = mp & 1;

      // ---- phase 1: pair cols + masked-unrolled corrections; spec stage ---
      float vk = 0.f, vk1 = 0.f;
      unsigned pk = 0;
      if (tid > k && tid < NF) {
        float2 pv = *(const float2*)&P[tid * PP + lc];
        vk = pv.x; vk1 = pv.y;
#pragma unroll
        for (int m = 0; m < PAIRS - 1; ++m) {
          float2 ti  = s_tc[m][tid];
          float2 tk  = s_tc[m][k];
          float2 tk1 = s_tc[m][k + 1];
          float im = s_invp[m];
          float d0 = im * (ti.x * tk.y  - ti.y * tk.x);
          float d1 = im * (ti.x * tk1.y - ti.y * tk1.x);
          vk  += (m < mp) ? d0 : 0.f;
          vk1 += (m < mp) ? d1 : 0.f;
        }
        s_colbuf[tid] = vk;
        if (tid > k + 1) s_tc[mp][tid] = make_float2(-vk, vk1);  // spec, RAW
        else             s_pivdef[par] = vk;                     // tid == k+1
        pk = (__float_as_uint(fabsf(vk)) & 0xFFFFFE00u) | (unsigned)tid;
      }
#pragma unroll
      for (int s = 32; s > 0; s >>= 1) {
        unsigned o = (unsigned)__shfl_xor((int)pk, s, 64);
        if (o > pk) pk = o;
      }
      if ((tid & 63) == 0) s_redu[par][tid >> 6] = pk;
      __syncthreads();                                    // B1 (only barrier)
      uint4 r0 = *(const uint4*)&s_redu[par][0];
      uint4 r1 = *(const uint4*)&s_redu[par][4];
      unsigned best = r0.x;
      best = best > r0.y ? best : r0.y;
      best = best > r0.z ? best : r0.z;
      best = best > r0.w ? best : r0.w;
      best = best > r1.x ? best : r1.x;
      best = best > r1.y ? best : r1.y;
      best = best > r1.z ? best : r1.z;
      best = best > r1.w ? best : r1.w;
      const float vmax = __uint_as_float(best & 0xFFFFFE00u);
      const float pivdef = -s_pivdef[par];
      const bool doswap = fabsf(pivdef) < THETA * vmax;

      if (!doswap) {
        // ========== common path: pivot = pivdef, NO LDS loads ==========
        const float invp = 1.f / pivdef;
        s_invp[mp] = invp;
        if (tid == 0) {
          sign *= (pivdef > 0.f ? 1.f : (pivdef < 0.f ? -1.f : 0.f));
          logabs += logf(fabsf(pivdef));
        }
      } else {
        const int kp = (int)(best & 0x1FFu);
        const float pivot = -s_colbuf[kp];
        const float invp = 1.f / pivot;
        s_invp[mp] = invp;
        if (tid == 0) {
          sign = -sign;
          sign *= (pivot > 0.f ? 1.f : (pivot < 0.f ? -1.f : 0.f));
          logabs += logf(fabsf(pivot));
        }
        const bool inpanel = (kp < pend);
        float gvr = 0.f;
        if (inpanel) {
          // ---- case B: in-panel swap ----
          const int lckp = kp - k0;
          if (tid > k + 1 && tid < NF && tid != kp) {
            float a = P[tid * PP + lc1], b2 = P[tid * PP + lckp];
            P[tid * PP + lc1] = b2; P[tid * PP + lckp] = a;
          } else if (tid >= NF && tid < NF + WP) {
            int c = tid - NF;
            if (c != lc1 && c != lckp) {
              float a = P[(k + 1) * PP + c], b2 = P[kp * PP + c];
              P[(k + 1) * PP + c] = b2; P[kp * PP + c] = a;
            }
          } else if (tid == NF + WP) {
            float a = P[kp * PP + lc1];         // old A[kp][k+1]
            float b2 = P[(k + 1) * PP + lckp];  // old A[k+1][kp]
            P[(k + 1) * PP + lc1] = 0.f;  P[(k + 1) * PP + lckp] = a;
            P[kp * PP + lc1] = b2;        P[kp * PP + lckp] = 0.f;
          } else if (tid >= NF + 24 && tid < NF + 24 + mp) {
            int m = tid - (NF + 24);
            float2 a = s_tc[m][k + 1], b2 = s_tc[m][kp];
            s_tc[m][k + 1] = b2; s_tc[m][kp] = a;
          }
        } else {
          // ---- case C: trailing swap, snapshot-consistent writeback ----
          if (tid >= pend && tid < NF) {
            if (tid == kp) {
              A[(size_t)kp * NF + kp] = 0.f;
            } else {
              float pvv = P[tid * PP + lc1];
              gvr = A[(size_t)tid * NF + kp];
              A[(size_t)tid * NF + kp] = pvv;
              A[(size_t)kp * NF + tid] = -pvv;
            }
          } else if (tid >= NF && tid < NF + WP) {
            int c = tid - NF;
            float old = P[kp * PP + c];
            s_oldrow[c] = old;
            P[kp * PP + c] = P[(k + 1) * PP + c];
          } else if (tid >= NF + 24 && tid < NF + 24 + mp) {
            int m = tid - (NF + 24);
            float2 a = s_tc[m][k + 1], b2 = s_tc[m][kp];
            s_tc[m][k + 1] = b2; s_tc[m][kp] = a;
          }
        }
        __syncthreads();                                  // B2
        // ---- restage (post-swap; corrections iv-folded, post-swap entries) -
        if (tid > k + 1 && tid < NF) {
          float vpost = (tid == kp) ? s_colbuf[k + 1] : vk;
          float cc;
          if (inpanel)        cc = P[tid * PP + lc1];
          else if (tid < pend) cc = -s_oldrow[tid - k0];
          else if (tid == kp)  cc = -s_oldrow[lc1];
          else                 cc = gvr;
#pragma unroll 1
          for (int m = 0; m < mp; ++m) {
            const float im = s_invp[m];
            float2 ti = s_tc[m][tid], tk1 = s_tc[m][k + 1];
            cc = fmaf(ti.x, im * tk1.y, fmaf(-ti.y, im * tk1.x, cc));
          }
          s_tc[mp][tid] = make_float2(-vpost, cc);        // RAW
        }
        __syncthreads();                                  // B3
      }
    }
    __syncthreads();   // all pairs staged + swap-path P reads done

    // ---- panel-end: single-pass j-outer trailing; stages next panel in P --
    if (pend < NF) {
      const int ty = tid >> 6, tx = tid & 63;   // 8 row streams x 64 col chunks
      const int nch = (NF - pend) >> 2;
      float ivr[PAIRS];
#pragma unroll
      for (int m = 0; m < PAIRS; ++m) ivr[m] = s_invp[m];
      for (int jb = 0; jb < nch; jb += 64) {
        const int j4 = jb + tx;
        if (j4 < nch) {
          const int j = pend + (j4 << 2);
          const bool stageP = (j4 < (WP >> 2));   // next panel's 16 cols
          float4 tj[PAIRS], cj[PAIRS];   // iv*nu_j, iv*c_j: 4 cols x 8 pairs
#pragma unroll
          for (int m = 0; m < PAIRS; ++m) {
            const float im = ivr[m];
            float4 q0 = *(const float4*)(&s_tc[m][j]);       // nu,c,nu,c
            float4 q1 = *(const float4*)(&s_tc[m][j + 2]);
            tj[m] = make_float4(q0.x * im, q0.z * im, q1.x * im, q1.z * im);
            cj[m] = make_float4(q0.y * im, q0.w * im, q1.y * im, q1.w * im);
          }
#pragma unroll 2
          for (int i = pend + ty; i < NF; i += 8) {
            float* ap = A + (size_t)i * NF + j;
            float4 a = *(float4*)ap;
#pragma unroll
            for (int m = 0; m < PAIRS; ++m) {
              const float2 t = s_tc[m][i];   // (nu_i, c_i) broadcast
              a.x = fmaf(t.x, cj[m].x, fmaf(-t.y, tj[m].x, a.x));
              a.y = fmaf(t.x, cj[m].y, fmaf(-t.y, tj[m].y, a.y));
              a.z = fmaf(t.x, cj[m].z, fmaf(-t.y, tj[m].z, a.z));
              a.w = fmaf(t.x, cj[m].w, fmaf(-t.y, tj[m].w, a.w));
            }
            *(float4*)ap = a;
            if (stageP) {
              float2* d = (float2*)&P[i * PP + (j - pend)];
              d[0] = make_float2(a.x, a.y);
              d[1] = make_float2(a.z, a.w);
            }
          }
        }
      }
    }
    __syncthreads();   // trailing + P staging visible before next factor
  }

  if (tid == 0) { out[b] = sign; out[NB + b] = logabs; }
}

extern "C" void kernel_launch(void* const* d_in, const int* in_sizes, int n_in,
                              void* d_out, int out_size, void* d_ws, size_t ws_size,
                              hipStream_t stream) {
  const float* U  = (const float*)d_in[0];
  const float* J  = (const float*)d_in[1];
  const int* idx  = (const int*)d_in[2];
  float* out = (float*)d_out;
  float* ws = (float*)d_ws;

  float* Ja  = ws;                          // 480*480
  float* Tmp = Ja + (size_t)NM * NM;        // 32*256*480
  float* Ff  = Tmp + (size_t)NB * NE * NM;  // 32*288*288

  build_ja_k<<<dim3(256), dim3(256), 0, stream>>>(J, Ja);
  gemm1_k<<<dim3(8, 4, NB), dim3(256), 0, stream>>>(U, idx, Ja, Tmp);
  gemm2_k<<<dim3(4, 4, NB), dim3(256), 0, stream>>>(U, idx, Tmp, Ff);
  fill_edges_k<<<dim3(NB), dim3(256), 0, stream>>>(U, idx, Ff);
  pfpanel_k<<<dim3(NB), dim3(512), 0, stream>>>(Ff, out);
}

// Round 16
// 331.525 us; speedup vs baseline: 2.1237x; 1.0676x over previous
//
#include <hip/hip_runtime.h>
#include <hip/hip_bf16.h>
#include <math.h>

#define NFM 512   // NFMODES
#define NE  256
#define NUN 32    // NUNPAIRED
#define NM  480   // NMODES
#define NB  32    // BATCH
#define NF  288   // NE + NUN  (Ffull dim)
#define WP  16    // panel width
#define PAIRS 8   // WP/2
#define PP  18    // panel LDS pitch (even -> float2-aligned)
#define THETA 0.03125f

typedef unsigned long long ull;

// ---------------- Ja = (J - J^T)/2 ----------------
__global__ __launch_bounds__(256)
void build_ja_k(const float* __restrict__ J, float* __restrict__ Ja) {
  int t = blockIdx.x * blockDim.x + threadIdx.x;
  int stride = gridDim.x * blockDim.x;
  for (int e = t; e < NM * NM; e += stride) {
    int i = e / NM, j = e - i * NM;
    Ja[e] = 0.5f * (J[i * NM + j] - J[j * NM + i]);
  }
}

// ---------------- W (512x480) = U[:, NUN:] @ Ja  (once, batch-independent) --
__global__ __launch_bounds__(256)
void gemm_w_k(const float* __restrict__ U, const float* __restrict__ Ja,
              float* __restrict__ W) {
  const int m0 = blockIdx.y << 6;
  const int n0 = blockIdx.x << 6;
  const int tid = threadIdx.x;
  __shared__ float As[16][64];
  __shared__ float Bs[16][64];
  const int ar = tid >> 2, ac = (tid & 3) << 2;
  const int br = tid >> 4, bc = (tid & 15) << 2;
  const int tx = tid & 15, ty = tid >> 4;
  const float* Arow = U + (size_t)(m0 + ar) * NFM + NUN;
  float acc[4][4] = {};
  for (int l0 = 0; l0 < NM; l0 += 16) {
    float4 av = *(const float4*)(Arow + l0 + ac);
    As[ac + 0][ar] = av.x; As[ac + 1][ar] = av.y;
    As[ac + 2][ar] = av.z; As[ac + 3][ar] = av.w;
    float4 bv = make_float4(0.f, 0.f, 0.f, 0.f);
    if (n0 + bc < NM) bv = *(const float4*)(Ja + (size_t)(l0 + br) * NM + n0 + bc);
    *(float4*)(&Bs[br][bc]) = bv;
    __syncthreads();
#pragma unroll
    for (int kk = 0; kk < 16; ++kk) {
      float4 a4 = *(const float4*)(&As[kk][ty << 2]);
      float4 b4 = *(const float4*)(&Bs[kk][tx << 2]);
      float a[4] = {a4.x, a4.y, a4.z, a4.w};
      float bb[4] = {b4.x, b4.y, b4.z, b4.w};
#pragma unroll
      for (int q = 0; q < 4; ++q)
#pragma unroll
        for (int p = 0; p < 4; ++p) acc[q][p] = fmaf(a[q], bb[p], acc[q][p]);
    }
    __syncthreads();
  }
#pragma unroll
  for (int q = 0; q < 4; ++q) {
    int r = m0 + (ty << 2) + q;
#pragma unroll
    for (int p = 0; p < 4; ++p) {
      int m = n0 + (tx << 2) + p;
      if (m < NM) W[(size_t)r * NM + m] = acc[q][p];
    }
  }
}

// ---------------- F[b] = W[idx[b]] @ Up_b^T  -> Ffull[0:256][0:256] ---------
// Antisymmetric: only blocks by>=bx computed; off-diagonal mirror-written.
__global__ __launch_bounds__(256)
void gemm2_k(const float* __restrict__ U, const int* __restrict__ idx,
             const float* __restrict__ W, float* __restrict__ Ff) {
  const int b  = blockIdx.z;
  const int by = blockIdx.y, bx = blockIdx.x;
  if (by < bx) return;
  const int m0 = by << 6;
  const int n0 = bx << 6;
  const int tid = threadIdx.x;
  __shared__ float As[16][64];
  __shared__ float Bs[16][64];
  const int ar = tid >> 2, ac = (tid & 3) << 2;
  const int jr = tid >> 2, kc = (tid & 3) << 2;
  const int tx = tid & 15, ty = tid >> 4;
  const float* Arow = W + (size_t)idx[b * NE + m0 + ar] * NM;
  const float* Brow = U + (size_t)idx[b * NE + n0 + jr] * NFM + NUN;
  float acc[4][4] = {};
  for (int l0 = 0; l0 < NM; l0 += 16) {
    float4 av = *(const float4*)(Arow + l0 + ac);
    As[ac + 0][ar] = av.x; As[ac + 1][ar] = av.y;
    As[ac + 2][ar] = av.z; As[ac + 3][ar] = av.w;
    float4 bv = *(const float4*)(Brow + l0 + kc);
    Bs[kc + 0][jr] = bv.x; Bs[kc + 1][jr] = bv.y;
    Bs[kc + 2][jr] = bv.z; Bs[kc + 3][jr] = bv.w;
    __syncthreads();
#pragma unroll
    for (int kk = 0; kk < 16; ++kk) {
      float4 a4 = *(const float4*)(&As[kk][ty << 2]);
      float4 b4 = *(const float4*)(&Bs[kk][tx << 2]);
      float a[4] = {a4.x, a4.y, a4.z, a4.w};
      float bb[4] = {b4.x, b4.y, b4.z, b4.w};
#pragma unroll
      for (int q = 0; q < 4; ++q)
#pragma unroll
        for (int p = 0; p < 4; ++p) acc[q][p] = fmaf(a[q], bb[p], acc[q][p]);
    }
    __syncthreads();
  }
  float* Fb = Ff + (size_t)b * NF * NF;
  const bool mirror = (by > bx);
#pragma unroll
  for (int q = 0; q < 4; ++q) {
    int i = m0 + (ty << 2) + q;
#pragma unroll
    for (int p = 0; p < 4; ++p) {
      int j = n0 + (tx << 2) + p;
      Fb[(size_t)i * NF + j] = acc[q][p];
      if (mirror) Fb[(size_t)j * NF + i] = -acc[q][p];
    }
  }
}

// ---------------- edges ---------------
__global__ __launch_bounds__(256)
void fill_edges_k(const float* __restrict__ U, const int* __restrict__ idx,
                  float* __restrict__ Ff) {
  const int b = blockIdx.x;
  const int tid = threadIdx.x;
  float* Fb = Ff + (size_t)b * NF * NF;
  const int gr = idx[b * NE + tid];
#pragma unroll 4
  for (int u = 0; u < NUN; ++u) {
    float v = U[(size_t)gr * NFM + u];
    Fb[(size_t)tid * NF + NE + u] = v;
    Fb[(size_t)(NE + u) * NF + tid] = -v;
  }
  if (tid < NUN) {
    for (int v = 0; v < NUN; ++v) Fb[(size_t)(NE + tid) * NF + NE + v] = 0.f;
  }
}

// ---------------- Pfaffian: R15 kernel verbatim (measured best) -------------
__global__ __launch_bounds__(512)
void pfpanel_k(float* __restrict__ Ff, float* __restrict__ out) {
  const int b = blockIdx.x;
  float* __restrict__ A = Ff + (size_t)b * NF * NF;
  const int tid = threadIdx.x;
  __shared__ __align__(16) float P[NF * PP];
  __shared__ __align__(16) float2 s_tc[PAIRS][NF];   // (nu, c) RAW
  __shared__ __align__(16) float s_colbuf[NF];
  __shared__ float s_oldrow[WP];
  __shared__ float s_pivdef[2];
  __shared__ float s_invp[PAIRS];
  __shared__ __align__(16) unsigned s_redu[2][8];

  float sign = 1.f, logabs = 0.f;   // thread 0 only

#pragma unroll 1
  for (int k0 = 0; k0 < NF; k0 += WP) {
    const int pend = k0 + WP;

    if (k0 == 0) {
      for (int e = tid; e < NF * 4; e += 512) {
        int r = e >> 2, c4 = (e & 3) << 2;
        float4 v = *(const float4*)(A + (size_t)r * NF + c4);
        float2* d = (float2*)&P[r * PP + c4];
        d[0] = make_float2(v.x, v.y);
        d[1] = make_float2(v.z, v.w);
      }
      __syncthreads();
    }

#pragma unroll 1
    for (int mp = 0; mp < PAIRS; ++mp) {
      const int k = k0 + 2 * mp, lc = 2 * mp, lc1 = lc + 1;
      const int par = mp & 1;

      float vk = 0.f, vk1 = 0.f;
      unsigned pk = 0;
      if (tid > k && tid < NF) {
        float2 pv = *(const float2*)&P[tid * PP + lc];
        vk = pv.x; vk1 = pv.y;
#pragma unroll
        for (int m = 0; m < PAIRS - 1; ++m) {
          float2 ti  = s_tc[m][tid];
          float2 tk  = s_tc[m][k];
          float2 tk1 = s_tc[m][k + 1];
          float im = s_invp[m];
          float d0 = im * (ti.x * tk.y  - ti.y * tk.x);
          float d1 = im * (ti.x * tk1.y - ti.y * tk1.x);
          vk  += (m < mp) ? d0 : 0.f;
          vk1 += (m < mp) ? d1 : 0.f;
        }
        s_colbuf[tid] = vk;
        if (tid > k + 1) s_tc[mp][tid] = make_float2(-vk, vk1);  // spec, RAW
        else             s_pivdef[par] = vk;                     // tid == k+1
        pk = (__float_as_uint(fabsf(vk)) & 0xFFFFFE00u) | (unsigned)tid;
      }
#pragma unroll
      for (int s = 32; s > 0; s >>= 1) {
        unsigned o = (unsigned)__shfl_xor((int)pk, s, 64);
        if (o > pk) pk = o;
      }
      if ((tid & 63) == 0) s_redu[par][tid >> 6] = pk;
      __syncthreads();                                    // B1 (only barrier)
      uint4 r0 = *(const uint4*)&s_redu[par][0];
      uint4 r1 = *(const uint4*)&s_redu[par][4];
      unsigned best = r0.x;
      best = best > r0.y ? best : r0.y;
      best = best > r0.z ? best : r0.z;
      best = best > r0.w ? best : r0.w;
      best = best > r1.x ? best : r1.x;
      best = best > r1.y ? best : r1.y;
      best = best > r1.z ? best : r1.z;
      best = best > r1.w ? best : r1.w;
      const float vmax = __uint_as_float(best & 0xFFFFFE00u);
      const float pivdef = -s_pivdef[par];
      const bool doswap = fabsf(pivdef) < THETA * vmax;

      if (!doswap) {
        const float invp = 1.f / pivdef;
        s_invp[mp] = invp;
        if (tid == 0) {
          sign *= (pivdef > 0.f ? 1.f : (pivdef < 0.f ? -1.f : 0.f));
          logabs += logf(fabsf(pivdef));
        }
      } else {
        const int kp = (int)(best & 0x1FFu);
        const float pivot = -s_colbuf[kp];
        const float invp = 1.f / pivot;
        s_invp[mp] = invp;
        if (tid == 0) {
          sign = -sign;
          sign *= (pivot > 0.f ? 1.f : (pivot < 0.f ? -1.f : 0.f));
          logabs += logf(fabsf(pivot));
        }
        const bool inpanel = (kp < pend);
        float gvr = 0.f;
        if (inpanel) {
          const int lckp = kp - k0;
          if (tid > k + 1 && tid < NF && tid != kp) {
            float a = P[tid * PP + lc1], b2 = P[tid * PP + lckp];
            P[tid * PP + lc1] = b2; P[tid * PP + lckp] = a;
          } else if (tid >= NF && tid < NF + WP) {
            int c = tid - NF;
            if (c != lc1 && c != lckp) {
              float a = P[(k + 1) * PP + c], b2 = P[kp * PP + c];
              P[(k + 1) * PP + c] = b2; P[kp * PP + c] = a;
            }
          } else if (tid == NF + WP) {
            float a = P[kp * PP + lc1];         // old A[kp][k+1]
            float b2 = P[(k + 1) * PP + lckp];  // old A[k+1][kp]
            P[(k + 1) * PP + lc1] = 0.f;  P[(k + 1) * PP + lckp] = a;
            P[kp * PP + lc1] = b2;        P[kp * PP + lckp] = 0.f;
          } else if (tid >= NF + 24 && tid < NF + 24 + mp) {
            int m = tid - (NF + 24);
            float2 a = s_tc[m][k + 1], b2 = s_tc[m][kp];
            s_tc[m][k + 1] = b2; s_tc[m][kp] = a;
          }
        } else {
          if (tid >= pend && tid < NF) {
            if (tid == kp) {
              A[(size_t)kp * NF + kp] = 0.f;
            } else {
              float pvv = P[tid * PP + lc1];
              gvr = A[(size_t)tid * NF + kp];
              A[(size_t)tid * NF + kp] = pvv;
              A[(size_t)kp * NF + tid] = -pvv;
            }
          } else if (tid >= NF && tid < NF + WP) {
            int c = tid - NF;
            float old = P[kp * PP + c];
            s_oldrow[c] = old;
            P[kp * PP + c] = P[(k + 1) * PP + c];
          } else if (tid >= NF + 24 && tid < NF + 24 + mp) {
            int m = tid - (NF + 24);
            float2 a = s_tc[m][k + 1], b2 = s_tc[m][kp];
            s_tc[m][k + 1] = b2; s_tc[m][kp] = a;
          }
        }
        __syncthreads();                                  // B2
        if (tid > k + 1 && tid < NF) {
          float vpost = (tid == kp) ? s_colbuf[k + 1] : vk;
          float cc;
          if (inpanel)        cc = P[tid * PP + lc1];
          else if (tid < pend) cc = -s_oldrow[tid - k0];
          else if (tid == kp)  cc = -s_oldrow[lc1];
          else                 cc = gvr;
#pragma unroll 1
          for (int m = 0; m < mp; ++m) {
            const float im = s_invp[m];
            float2 ti = s_tc[m][tid], tk1 = s_tc[m][k + 1];
            cc = fmaf(ti.x, im * tk1.y, fmaf(-ti.y, im * tk1.x, cc));
          }
          s_tc[mp][tid] = make_float2(-vpost, cc);        // RAW
        }
        __syncthreads();                                  // B3
      }
    }
    __syncthreads();   // all pairs staged + swap-path P reads done

    if (pend < NF) {
      const int ty = tid >> 6, tx = tid & 63;
      const int nch = (NF - pend) >> 2;
      float ivr[PAIRS];
#pragma unroll
      for (int m = 0; m < PAIRS; ++m) ivr[m] = s_invp[m];
      for (int jb = 0; jb < nch; jb += 64) {
        const int j4 = jb + tx;
        if (j4 < nch) {
          const int j = pend + (j4 << 2);
          const bool stageP = (j4 < (WP >> 2));
          float4 tj[PAIRS], cj[PAIRS];
#pragma unroll
          for (int m = 0; m < PAIRS; ++m) {
            const float im = ivr[m];
            float4 q0 = *(const float4*)(&s_tc[m][j]);
            float4 q1 = *(const float4*)(&s_tc[m][j + 2]);
            tj[m] = make_float4(q0.x * im, q0.z * im, q1.x * im, q1.z * im);
            cj[m] = make_float4(q0.y * im, q0.w * im, q1.y * im, q1.w * im);
          }
#pragma unroll 2
          for (int i = pend + ty; i < NF; i += 8) {
            float* ap = A + (size_t)i * NF + j;
            float4 a = *(float4*)ap;
#pragma unroll
            for (int m = 0; m < PAIRS; ++m) {
              const float2 t = s_tc[m][i];
              a.x = fmaf(t.x, cj[m].x, fmaf(-t.y, tj[m].x, a.x));
              a.y = fmaf(t.x, cj[m].y, fmaf(-t.y, tj[m].y, a.y));
              a.z = fmaf(t.x, cj[m].z, fmaf(-t.y, tj[m].z, a.z));
              a.w = fmaf(t.x, cj[m].w, fmaf(-t.y, tj[m].w, a.w));
            }
            *(float4*)ap = a;
            if (stageP) {
              float2* d = (float2*)&P[i * PP + (j - pend)];
              d[0] = make_float2(a.x, a.y);
              d[1] = make_float2(a.z, a.w);
            }
          }
        }
      }
    }
    __syncthreads();
  }

  if (tid == 0) { out[b] = sign; out[NB + b] = logabs; }
}

extern "C" void kernel_launch(void* const* d_in, const int* in_sizes, int n_in,
                              void* d_out, int out_size, void* d_ws, size_t ws_size,
                              hipStream_t stream) {
  const float* U  = (const float*)d_in[0];
  const float* J  = (const float*)d_in[1];
  const int* idx  = (const int*)d_in[2];
  float* out = (float*)d_out;
  float* ws = (float*)d_ws;

  float* Ja = ws;                           // 480*480   = 230400 floats
  float* W  = Ja + (size_t)NM * NM;         // 512*480   = 245760 floats
  float* Ff = W + (size_t)NFM * NM;         // 32*288*288

  build_ja_k<<<dim3(256), dim3(256), 0, stream>>>(J, Ja);
  gemm_w_k<<<dim3(8, 8), dim3(256), 0, stream>>>(U, Ja, W);
  gemm2_k<<<dim3(4, 4, NB), dim3(256), 0, stream>>>(U, idx, W, Ff);
  fill_edges_k<<<dim3(NB), dim3(256), 0, stream>>>(U, idx, Ff);
  pfpanel_k<<<dim3(NB), dim3(512), 0, stream>>>(Ff, out);
}